// Round 6
// baseline (2288.834 us; speedup 1.0000x reference)
//
#include <hip/hip_runtime.h>

#define NNODES 50000
#define NEDGES 400000

// ---- node-kernel tile params ----
#define TE 16
#define AP 18
#define VP 50

// ---- edge-kernel params ----
// ET=8 edges / 64 threads = ONE wave per block (R3 structure, 1667us) +
// register prefetch of next-kt gathers + unroll-8 on single-stream W loops.
#define ET 8
#define QW 12      // Q / A2 row stride (ET + pad, multiple of 4 for float4)
#define SW 132     // sbuf row stride (128 + 4)
#define VW 26      // V row stride (3*ET + 2)
#define MW 260     // LDS message row stride (float4-aligned)

// shared pool layout (floats)
#define OFF_Q   0
#define OFF_VC  1536            // 128*12
#define OFF_SB  3200            // + 64*26
#define POOLSZ  4256            // + 8*132

constexpr float RSQRT3 = 0.57735026918962576f;
constexpr float INV_M1 = 0.062257280630559f;   // 1/sqrt(130+128)
constexpr float INV_M2 = 0.088388347648318f;   // 1/sqrt(64+64)
constexpr float INV_U0 = 0.0625f;              // 1/sqrt(128+128)
constexpr float INV_U1 = 0.088388347648318f;   // 1/sqrt(64+64)

__device__ __forceinline__ float fast_sigmoid(float x){ return 1.0f / (1.0f + __expf(-x)); }

// =====================================================================
// CSR-build kernels (ws cost: ~2 MB)
// =====================================================================
__global__ __launch_bounds__(256) void hist_kernel(const int* __restrict__ recv, int* __restrict__ cnt){
  const int e = blockIdx.x * 256 + threadIdx.x;
  if (e < NEDGES) atomicAdd(&cnt[recv[e]], 1);
}

__global__ __launch_bounds__(1024) void scan_kernel(const int* __restrict__ cnt, int* __restrict__ offs){
  __shared__ int ssum[1024];
  const int t = threadIdx.x;
  const int C = (NNODES + 1023) / 1024;   // 49
  const int base = t * C;
  int s = 0;
  for (int i = 0; i < C; i++){
    const int idx = base + i;
    if (idx < NNODES) s += cnt[idx];
  }
  ssum[t] = s;
  __syncthreads();
  for (int off = 1; off < 1024; off <<= 1){
    int v = (t >= off) ? ssum[t - off] : 0;
    __syncthreads();
    ssum[t] += v;
    __syncthreads();
  }
  int run = (t == 0) ? 0 : ssum[t - 1];
  for (int i = 0; i < C; i++){
    const int idx = base + i;
    if (idx < NNODES){ offs[idx] = run; run += cnt[idx]; }
  }
  if (t == 1023) offs[NNODES] = run;
}

__global__ __launch_bounds__(256) void place_kernel(const int* __restrict__ recv,
                                                    const int* __restrict__ offs,
                                                    int* __restrict__ cur,
                                                    int* __restrict__ elist){
  const int e = blockIdx.x * 256 + threadIdx.x;
  if (e < NEDGES){
    const int r = recv[e];
    const int p = atomicAdd(&cur[r], 1);
    elist[offs[r] + p] = e;
  }
}

// =====================================================================
// EDGE KERNEL: 8 edges / 64 threads (single wave). m1 (gated) -> m2 (gated) ->
// MODE 1: receiver-sorted edges, LDS run-length combine, mostly plain stores
// MODE 0: direct atomic scatter fallback
// =====================================================================
template<int MODE>
__global__ __launch_bounds__(64, 2) void edge_kernel(
    const float* __restrict__ node_s, const float* __restrict__ node_v,
    const float* __restrict__ edge_attr_s, const float* __restrict__ edge_attr_v,
    const float* __restrict__ add_feat,
    const int* __restrict__ senders, const int* __restrict__ receivers,
    const int* __restrict__ elist,
    const float* __restrict__ Wss1, const float* __restrict__ Wvs1,
    const float* __restrict__ Wsv1, const float* __restrict__ Wvv1,
    const float* __restrict__ b1,
    const float* __restrict__ Wss2, const float* __restrict__ Wvs2,
    const float* __restrict__ Wsv2, const float* __restrict__ Wvv2,
    const float* __restrict__ b2,
    float* __restrict__ out)
{
  __shared__ __align__(16) float pool[POOLSZ];
  __shared__ __align__(16) float af_sh[2][QW];
  __shared__ float as_sh[ET], av0_sh[ET], av1_sh[ET], av2_sh[ET];
  __shared__ int snd_sh[ET], rcv_sh[ET], eid_sh[ET];

  float (*Qreg)[QW] = (float(*)[QW])(pool + OFF_Q);
  float (*VC)[VW]   = (float(*)[VW])(pool + OFF_VC);
  float (*sbuf)[SW] = (float(*)[SW])(pool + OFF_SB);
  float (*A2)[QW]   = (float(*)[QW])(pool + OFF_VC);   // phase-2 view of VC
  float* msgL = pool;                                   // epilogue overlay, stride MW

  const int t   = threadIdx.x;
  const int e0  = blockIdx.x * ET;
  const int og5 = t & 31, eg5 = t >> 5;
  const int og4 = t & 15, eg4 = t >> 4;

  if (t < ET) eid_sh[t] = MODE ? elist[e0 + t] : (e0 + t);
  __syncthreads();

  if (t < ET){
    const int eid = eid_sh[t];
    as_sh[t]  = edge_attr_s[eid];
    snd_sh[t] = senders[eid];
    rcv_sh[t] = receivers[eid];
  } else if (t < 2*ET){
    const int e = t - ET;
    const int eid = eid_sh[e];
    av0_sh[e] = edge_attr_v[(size_t)eid*3 + 0];
    av1_sh[e] = edge_attr_v[(size_t)eid*3 + 1];
    av2_sh[e] = edge_attr_v[(size_t)eid*3 + 2];
  } else if (t < 4*ET){
    const int x = t - 2*ET, e = x >> 1, d = x & 1;
    af_sh[d][e] = add_feat[(size_t)eid_sh[e]*2 + d];
  }
  __syncthreads();

  // per-thread gather role: 8 threads per edge
  const int e8 = t >> 3, q8 = t & 7;
  const float pa0 = av0_sh[e8], pa1 = av1_sh[e8], pa2 = av2_sh[e8];

  // ================= phase 1: V-tiles -> gemm_u(Wvv1) + build Q =================
  // register-prefetched gathers: load kt+1's node_v while kt's W-gemm runs
  float4 pf0, pf1, pf2;   // node_v prefetch (3 x float4)
  float4 pg;              // node_s prefetch for phase 2 (issued during phase-1 kt=3)
  {
    const int n = snd_sh[e8];
    const float4* src = (const float4*)(node_v + (size_t)n*192) + q8*3;
    pf0 = src[0]; pf1 = src[1]; pf2 = src[2];
  }
  float accU[3][4][2] = {};
  for (int kt = 0; kt < 4; kt++){
    {
      const float f[12] = {pf0.x,pf0.y,pf0.z,pf0.w, pf1.x,pf1.y,pf1.z,pf1.w,
                           pf2.x,pf2.y,pf2.z,pf2.w};
      #pragma unroll
      for (int d = 0; d < 4; d++){
        const int r = q8*4 + d;
        VC[r][0*ET + e8] = f[d*3+0];
        VC[r][1*ET + e8] = f[d*3+1];
        VC[r][2*ET + e8] = f[d*3+2];
        Qreg[kt*32 + r][e8] = (f[d*3]*pa0 + f[d*3+1]*pa1 + f[d*3+2]*pa2) * RSQRT3;
      }
    }
    __syncthreads();
    // issue next gather now; it completes under the W-gemm below
    if (kt < 3){
      const int n = (kt+1 < 2) ? snd_sh[e8] : rcv_sh[e8];
      const float4* src = (const float4*)(node_v + (size_t)n*192) + ((kt+1)&1)*24 + q8*3;
      pf0 = src[0]; pf1 = src[1]; pf2 = src[2];
    } else {
      const int n = snd_sh[e8];
      pg = ((const float4*)(node_s + (size_t)n*64))[q8];
    }
    const float4* W4 = (const float4*)Wvv1 + (size_t)(kt*32)*16 + og4;
    #pragma unroll 4
    for (int r = 0; r < 32; r++){
      const float4 wv = W4[(size_t)r*16];
      const float w[4] = {wv.x, wv.y, wv.z, wv.w};
      const float2 a0 = *(const float2*)&VC[r][0*ET + eg4*2];
      const float2 a1 = *(const float2*)&VC[r][1*ET + eg4*2];
      const float2 a2 = *(const float2*)&VC[r][2*ET + eg4*2];
      const float av0a[2] = {a0.x, a0.y}, av1a[2] = {a1.x, a1.y}, av2a[2] = {a2.x, a2.y};
      #pragma unroll
      for (int j = 0; j < 4; j++){
        #pragma unroll
        for (int m = 0; m < 2; m++){
          accU[0][j][m] = fmaf(w[j], av0a[m], accU[0][j][m]);
          accU[1][j][m] = fmaf(w[j], av1a[m], accU[1][j][m]);
          accU[2][j][m] = fmaf(w[j], av2a[m], accU[2][j][m]);
        }
      }
    }
    __syncthreads();
  }

  // ================= phase 2: xs-tiles -> gemm_s(Wss1) + gemm_t(Wsv1) =================
  float accS[4][4] = {};
  float accT[4][2] = {};
  for (int kt = 0; kt < 4; kt++){
    {
      A2[q8*4+0][e8] = pg.x; A2[q8*4+1][e8] = pg.y;
      A2[q8*4+2][e8] = pg.z; A2[q8*4+3][e8] = pg.w;
    }
    __syncthreads();
    if (kt < 3){
      const int n = (kt+1 < 2) ? snd_sh[e8] : rcv_sh[e8];
      pg = ((const float4*)(node_s + (size_t)n*64))[((kt+1)&1)*8 + q8];
    }
    const float4* Wa = (const float4*)Wss1 + (size_t)(kt*32)*32 + og5;
    const float4* Wb = (const float4*)Wsv1 + (size_t)(kt*32)*16 + og4;
    #pragma unroll 4
    for (int r = 0; r < 32; r++){
      const float4 wav = Wa[(size_t)r*32];
      const float wa[4] = {wav.x, wav.y, wav.z, wav.w};
      const float4 a4 = *(const float4*)&A2[r][eg5*4];
      const float aa[4] = {a4.x, a4.y, a4.z, a4.w};
      #pragma unroll
      for (int j = 0; j < 4; j++)
        #pragma unroll
        for (int m = 0; m < 4; m++)
          accS[j][m] = fmaf(wa[j], aa[m], accS[j][m]);
      const float4 wbv = Wb[(size_t)r*16];
      const float wb[4] = {wbv.x, wbv.y, wbv.z, wbv.w};
      const float2 a2v = *(const float2*)&A2[r][eg4*2];
      const float ab[2] = {a2v.x, a2v.y};
      #pragma unroll
      for (int j = 0; j < 4; j++)
        #pragma unroll
        for (int m = 0; m < 2; m++)
          accT[j][m] = fmaf(wb[j], ab[m], accT[j][m]);
    }
    __syncthreads();
  }
  // tail rows 128..129 (add_feat)
  #pragma unroll
  for (int d = 0; d < 2; d++){
    const float4 wav = ((const float4*)Wss1)[(size_t)(128+d)*32 + og5];
    const float wa[4] = {wav.x, wav.y, wav.z, wav.w};
    const float4 a4 = *(const float4*)&af_sh[d][eg5*4];
    const float aa[4] = {a4.x, a4.y, a4.z, a4.w};
    #pragma unroll
    for (int j = 0; j < 4; j++)
      #pragma unroll
      for (int m = 0; m < 4; m++)
        accS[j][m] = fmaf(wa[j], aa[m], accS[j][m]);
    const float4 wbv = ((const float4*)Wsv1)[(size_t)(128+d)*16 + og4];
    const float wb[4] = {wbv.x, wbv.y, wbv.z, wbv.w};
    const float ab[2] = {af_sh[d][eg4*2], af_sh[d][eg4*2+1]};
    #pragma unroll
    for (int j = 0; j < 4; j++)
      #pragma unroll
      for (int m = 0; m < 2; m++)
        accT[j][m] = fmaf(wb[j], ab[m], accT[j][m]);
  }

  // ================= phase 3: gemm_s(Wvs1) over resident Q =================
  float accV[4][4] = {};
  {
    const float4* Wc = (const float4*)Wvs1 + og5;
    #pragma unroll 8
    for (int k = 0; k < 128; k++){
      const float4 wv = Wc[(size_t)k*32];
      const float w[4] = {wv.x, wv.y, wv.z, wv.w};
      const float4 a4 = *(const float4*)&Qreg[k][eg5*4];
      const float aa[4] = {a4.x, a4.y, a4.z, a4.w};
      #pragma unroll
      for (int j = 0; j < 4; j++)
        #pragma unroll
        for (int m = 0; m < 4; m++)
          accV[j][m] = fmaf(w[j], aa[m], accV[j][m]);
    }
  }
  {
    const float4 b1v = ((const float4*)b1)[og5];
    const float bb[4] = {b1v.x, b1v.y, b1v.z, b1v.w};
    #pragma unroll
    for (int m = 0; m < 4; m++){
      const int e = eg5*4 + m;
      const float as = as_sh[e];
      float4 s1;
      s1.x = (as*accS[0][m] + accV[0][m]) * INV_M1 + bb[0];
      s1.y = (as*accS[1][m] + accV[1][m]) * INV_M1 + bb[1];
      s1.z = (as*accS[2][m] + accV[2][m]) * INV_M1 + bb[2];
      s1.w = (as*accS[3][m] + accV[3][m]) * INV_M1 + bb[3];
      *(float4*)&sbuf[e][og5*4] = s1;
    }
  }
  __syncthreads();

  // ================= m1 epilogue =================
  {
    #pragma unroll
    for (int m = 0; m < 2; m++){
      const int e = eg4*2 + m;
      const float as = as_sh[e];
      const float a0 = av0_sh[e], a1 = av1_sh[e], a2 = av2_sh[e];
      #pragma unroll
      for (int j = 0; j < 4; j++){
        const int o = og4*4 + j;
        const float s1a = sbuf[e][o];
        const float s1b = sbuf[e][64 + o];
        const float ms = s1a * fast_sigmoid(s1a);
        const float g  = fast_sigmoid(s1b);
        const float tt = accT[j][m];
        const float mv0 = (tt*a0 + as*accU[0][j][m]) * INV_M1 * g;
        const float mv1 = (tt*a1 + as*accU[1][j][m]) * INV_M1 * g;
        const float mv2 = (tt*a2 + as*accU[2][j][m]) * INV_M1 * g;
        Qreg[o][e]      = ms;
        Qreg[64 + o][e] = (mv0*a0 + mv1*a1 + mv2*a2) * RSQRT3;
        VC[o][0*ET + e] = mv0; VC[o][1*ET + e] = mv1; VC[o][2*ET + e] = mv2;
      }
    }
  }
  __syncthreads();

  // ================= m2 =================
  float acc2S[4][4] = {};
  {
    const float4* Wd = (const float4*)Wss2 + og5;
    #pragma unroll 8
    for (int k = 0; k < 64; k++){
      const float4 wv = Wd[(size_t)k*32];
      const float w[4] = {wv.x, wv.y, wv.z, wv.w};
      const float4 a4 = *(const float4*)&Qreg[k][eg5*4];
      const float aa[4] = {a4.x, a4.y, a4.z, a4.w};
      #pragma unroll
      for (int j = 0; j < 4; j++)
        #pragma unroll
        for (int m = 0; m < 4; m++)
          acc2S[j][m] = fmaf(w[j], aa[m], acc2S[j][m]);
    }
  }
  float acc2V[4][4] = {};
  {
    const float4* We = (const float4*)Wvs2 + og5;
    #pragma unroll 8
    for (int k = 0; k < 64; k++){
      const float4 wv = We[(size_t)k*32];
      const float w[4] = {wv.x, wv.y, wv.z, wv.w};
      const float4 a4 = *(const float4*)&Qreg[64 + k][eg5*4];
      const float aa[4] = {a4.x, a4.y, a4.z, a4.w};
      #pragma unroll
      for (int j = 0; j < 4; j++)
        #pragma unroll
        for (int m = 0; m < 4; m++)
          acc2V[j][m] = fmaf(w[j], aa[m], acc2V[j][m]);
    }
  }
  {
    const float4 b2v = ((const float4*)b2)[og5];
    const float bb[4] = {b2v.x, b2v.y, b2v.z, b2v.w};
    #pragma unroll
    for (int m = 0; m < 4; m++){
      const int e = eg5*4 + m;
      const float as = as_sh[e];
      float4 s2;
      s2.x = (as*acc2S[0][m] + acc2V[0][m]) * INV_M2 + bb[0];
      s2.y = (as*acc2S[1][m] + acc2V[1][m]) * INV_M2 + bb[1];
      s2.z = (as*acc2S[2][m] + acc2V[2][m]) * INV_M2 + bb[2];
      s2.w = (as*acc2S[3][m] + acc2V[3][m]) * INV_M2 + bb[3];
      *(float4*)&sbuf[e][og5*4] = s2;
    }
  }
  float acc2T[4][2] = {};
  {
    const float4* Wf = (const float4*)Wsv2 + og4;
    #pragma unroll 8
    for (int k = 0; k < 64; k++){
      const float4 wv = Wf[(size_t)k*16];
      const float w[4] = {wv.x, wv.y, wv.z, wv.w};
      const float2 a2v = *(const float2*)&Qreg[k][eg4*2];
      const float aa[2] = {a2v.x, a2v.y};
      #pragma unroll
      for (int j = 0; j < 4; j++)
        #pragma unroll
        for (int m = 0; m < 2; m++)
          acc2T[j][m] = fmaf(w[j], aa[m], acc2T[j][m]);
    }
  }
  float acc2U[3][4][2] = {};
  {
    const float4* Wg = (const float4*)Wvv2 + og4;
    #pragma unroll 8
    for (int k = 0; k < 64; k++){
      const float4 wv = Wg[(size_t)k*16];
      const float w[4] = {wv.x, wv.y, wv.z, wv.w};
      const float2 a0 = *(const float2*)&VC[k][0*ET + eg4*2];
      const float2 a1 = *(const float2*)&VC[k][1*ET + eg4*2];
      const float2 a2 = *(const float2*)&VC[k][2*ET + eg4*2];
      const float av0a[2] = {a0.x, a0.y}, av1a[2] = {a1.x, a1.y}, av2a[2] = {a2.x, a2.y};
      #pragma unroll
      for (int j = 0; j < 4; j++)
        #pragma unroll
        for (int m = 0; m < 2; m++){
          acc2U[0][j][m] = fmaf(w[j], av0a[m], acc2U[0][j][m]);
          acc2U[1][j][m] = fmaf(w[j], av1a[m], acc2U[1][j][m]);
          acc2U[2][j][m] = fmaf(w[j], av2a[m], acc2U[2][j][m]);
        }
    }
  }
  __syncthreads();   // Qreg/VC now dead -> msgL overlay is safe (sbuf still live)

  // ================= final epilogue =================
  if (MODE == 1){
    // write per-edge 256-float messages into LDS (overlay on Qreg+VC)
    #pragma unroll
    for (int m = 0; m < 2; m++){
      const int e = eg4*2 + m;
      const float as = as_sh[e];
      const float a0 = av0_sh[e], a1 = av1_sh[e], a2 = av2_sh[e];
      float* base = msgL + e*MW;
      float4 sv;
      float vv[12];
      #pragma unroll
      for (int j = 0; j < 4; j++){
        const int o = og4*4 + j;
        const float s2a = sbuf[e][o];
        const float s2b = sbuf[e][64 + o];
        ((float*)&sv)[j] = s2a * fast_sigmoid(s2a);
        const float g  = fast_sigmoid(s2b);
        const float tt = acc2T[j][m];
        vv[j*3 + 0] = (tt*a0 + as*acc2U[0][j][m]) * INV_M2 * g;
        vv[j*3 + 1] = (tt*a1 + as*acc2U[1][j][m]) * INV_M2 * g;
        vv[j*3 + 2] = (tt*a2 + as*acc2U[2][j][m]) * INV_M2 * g;
      }
      *(float4*)(base + og4*4) = sv;
      float4* vp = (float4*)(base + 64 + og4*12);
      vp[0] = make_float4(vv[0], vv[1], vv[2], vv[3]);
      vp[1] = make_float4(vv[4], vv[5], vv[6], vv[7]);
      vp[2] = make_float4(vv[8], vv[9], vv[10], vv[11]);
    }
    __syncthreads();
    // run-length combine over sorted receivers; each thread owns 4 features
    {
      const int f0 = t;
      float acc0 = 0.f, acc1 = 0.f, acc2 = 0.f, acc3 = 0.f;
      int seg_start = 0;
      for (int ee = 0; ee < ET; ee++){
        acc0 += msgL[ee*MW + f0];
        acc1 += msgL[ee*MW + f0 + 64];
        acc2 += msgL[ee*MW + f0 + 128];
        acc3 += msgL[ee*MW + f0 + 192];
        const int r = rcv_sh[ee];
        const bool last = (ee == ET-1);
        if (last || rcv_sh[ee+1] != r){
          float* dst = out + (size_t)r * 256;
          if (seg_start == 0 || last){       // run touches block boundary
            atomicAdd(dst + f0,       acc0);
            atomicAdd(dst + f0 + 64,  acc1);
            atomicAdd(dst + f0 + 128, acc2);
            atomicAdd(dst + f0 + 192, acc3);
          } else {                           // receiver fully owned by block
            dst[f0]       = acc0;
            dst[f0 + 64]  = acc1;
            dst[f0 + 128] = acc2;
            dst[f0 + 192] = acc3;
          }
          acc0 = 0.f; acc1 = 0.f; acc2 = 0.f; acc3 = 0.f;
          seg_start = ee + 1;
        }
      }
    }
  } else {
    #pragma unroll
    for (int m = 0; m < 2; m++){
      const int e = eg4*2 + m;
      const float as = as_sh[e];
      const float a0 = av0_sh[e], a1 = av1_sh[e], a2 = av2_sh[e];
      float* base = out + (size_t)rcv_sh[e] * 256;
      #pragma unroll
      for (int j = 0; j < 4; j++){
        const int o = og4*4 + j;
        const float s2a = sbuf[e][o];
        const float s2b = sbuf[e][64 + o];
        atomicAdd(base + o, s2a * fast_sigmoid(s2a));
        const float g  = fast_sigmoid(s2b);
        const float tt = acc2T[j][m];
        atomicAdd(base + 64 + o*3 + 0, (tt*a0 + as*acc2U[0][j][m]) * INV_M2 * g);
        atomicAdd(base + 64 + o*3 + 1, (tt*a1 + as*acc2U[1][j][m]) * INV_M2 * g);
        atomicAdd(base + 64 + o*3 + 2, (tt*a2 + as*acc2U[2][j][m]) * INV_M2 * g);
      }
    }
  }
}

// =====================================================================
// NODE KERNEL: u0 (gated) -> u1 -> residual
// =====================================================================
template<int K, int ROWBASE>
__device__ __forceinline__ void gemm_s_n(float acc[4][2], const float* __restrict__ W,
                                         float (*A_T)[AP], int t){
  const int og = t & 31;
  const int eg = t >> 5;
  const float4* __restrict__ W4 = (const float4*)W;
  #pragma unroll 8
  for (int k = 0; k < K; k++){
    const float4 w = W4[k*32 + og];
    const float2 a = *(const float2*)(&A_T[ROWBASE + k][eg*2]);
    acc[0][0] = fmaf(w.x, a.x, acc[0][0]); acc[0][1] = fmaf(w.x, a.y, acc[0][1]);
    acc[1][0] = fmaf(w.y, a.x, acc[1][0]); acc[1][1] = fmaf(w.y, a.y, acc[1][1]);
    acc[2][0] = fmaf(w.z, a.x, acc[2][0]); acc[2][1] = fmaf(w.z, a.y, acc[2][1]);
    acc[3][0] = fmaf(w.w, a.x, acc[3][0]); acc[3][1] = fmaf(w.w, a.y, acc[3][1]);
  }
}

template<int K, int ROWBASE>
__device__ __forceinline__ void gemm_t_n(float acc[4], const float* __restrict__ W,
                                         float (*A_T)[AP], int t){
  const int og = t & 15;
  const int eg = t >> 4;
  const float4* __restrict__ W4 = (const float4*)W;
  #pragma unroll 8
  for (int k = 0; k < K; k++){
    const float4 w = W4[k*16 + og];
    const float a = A_T[ROWBASE + k][eg];
    acc[0] = fmaf(w.x, a, acc[0]); acc[1] = fmaf(w.y, a, acc[1]);
    acc[2] = fmaf(w.z, a, acc[2]); acc[3] = fmaf(w.w, a, acc[3]);
  }
}

template<int K>
__device__ __forceinline__ void gemm_u_n(float acc[3][4], const float* __restrict__ W,
                                         float (*V_T)[VP], int t){
  const int og = t & 15;
  const int eg = t >> 4;
  const float4* __restrict__ W4 = (const float4*)W;
  #pragma unroll 4
  for (int k = 0; k < K; k++){
    const float4 w = W4[k*16 + og];
    const float a0 = V_T[k][eg], a1 = V_T[k][16+eg], a2 = V_T[k][32+eg];
    acc[0][0] = fmaf(w.x,a0,acc[0][0]); acc[0][1] = fmaf(w.y,a0,acc[0][1]);
    acc[0][2] = fmaf(w.z,a0,acc[0][2]); acc[0][3] = fmaf(w.w,a0,acc[0][3]);
    acc[1][0] = fmaf(w.x,a1,acc[1][0]); acc[1][1] = fmaf(w.y,a1,acc[1][1]);
    acc[1][2] = fmaf(w.z,a1,acc[1][2]); acc[1][3] = fmaf(w.w,a1,acc[1][3]);
    acc[2][0] = fmaf(w.x,a2,acc[2][0]); acc[2][1] = fmaf(w.y,a2,acc[2][1]);
    acc[2][2] = fmaf(w.z,a2,acc[2][2]); acc[2][3] = fmaf(w.w,a2,acc[2][3]);
  }
}

__global__ __launch_bounds__(256, 3) void node_kernel(
    const float* __restrict__ node_s, const float* __restrict__ node_v,
    const float* __restrict__ node_attr_s, const float* __restrict__ node_attr_v,
    const float* __restrict__ Wss0, const float* __restrict__ Wvs0,
    const float* __restrict__ Wsv0, const float* __restrict__ Wvv0,
    const float* __restrict__ b0,
    const float* __restrict__ Wss1, const float* __restrict__ Wvs1,
    const float* __restrict__ Wsv1, const float* __restrict__ Wvv1,
    const float* __restrict__ b1u,
    float* __restrict__ out)
{
  __shared__ float A_T[256][AP];
  __shared__ float V_T[128][VP];
  __shared__ float s_buf[TE][129];
  __shared__ float a_s_sh[TE];
  __shared__ float av_sh[TE][3];

  const int t = threadIdx.x;
  const int n0 = blockIdx.x * TE;

  if (t < TE) a_s_sh[t] = node_attr_s[n0 + t];
  if (t < TE*3) av_sh[t/3][t%3] = node_attr_v[n0*3 + t];
  {
    const int e = t >> 4, l = t & 15;
    const int n = n0 + e;
    float4 v4 = ((const float4*)(node_s + (size_t)n*64))[l];
    A_T[l*4+0][e] = v4.x; A_T[l*4+1][e] = v4.y;
    A_T[l*4+2][e] = v4.z; A_T[l*4+3][e] = v4.w;
    v4 = ((const float4*)(out + (size_t)n*256))[l];
    A_T[64+l*4+0][e] = v4.x; A_T[64+l*4+1][e] = v4.y;
    A_T[64+l*4+2][e] = v4.z; A_T[64+l*4+3][e] = v4.w;
    const float4* pvn = (const float4*)(node_v + (size_t)n*192);
    const float4* pva = (const float4*)(out + (size_t)n*256 + 64);
    #pragma unroll
    for (int q = 0; q < 3; q++){
      float4 w4 = pvn[l*3+q];
      int f = (l*3+q)*4;
      float vals[4] = {w4.x, w4.y, w4.z, w4.w};
      #pragma unroll
      for (int j = 0; j < 4; j++){
        int ff = f + j, vv = ff/3, ii = ff - vv*3;
        V_T[vv][ii*16 + e] = vals[j];
      }
      w4 = pva[l*3+q];
      float vals2[4] = {w4.x, w4.y, w4.z, w4.w};
      #pragma unroll
      for (int j = 0; j < 4; j++){
        int ff = f + j, vv = ff/3, ii = ff - vv*3;
        V_T[64 + vv][ii*16 + e] = vals2[j];
      }
    }
  }
  __syncthreads();
  {
    const int e = t >> 4, l = t & 15;
    const float a0 = av_sh[e][0], a1 = av_sh[e][1], a2 = av_sh[e][2];
    #pragma unroll
    for (int r = 0; r < 8; r++){
      int v = l*8 + r;
      float q = V_T[v][e]*a0 + V_T[v][16+e]*a1 + V_T[v][32+e]*a2;
      A_T[128 + v][e] = q * RSQRT3;
    }
  }
  __syncthreads();

  float acc_a[4][2] = {{0.f,0.f},{0.f,0.f},{0.f,0.f},{0.f,0.f}};
  float acc_b[4][2] = {{0.f,0.f},{0.f,0.f},{0.f,0.f},{0.f,0.f}};
  gemm_s_n<128, 0>(acc_a, Wss0, A_T, t);
  gemm_s_n<128, 128>(acc_b, Wvs0, A_T, t);
  {
    const int og = t & 31, eg = t >> 5;
    #pragma unroll
    for (int m = 0; m < 2; m++){
      const int e = eg*2 + m;
      const float as = a_s_sh[e];
      #pragma unroll
      for (int j = 0; j < 4; j++){
        const int o = og*4 + j;
        s_buf[e][o] = (as*acc_a[j][m] + acc_b[j][m]) * INV_U0 + b0[o];
      }
    }
  }
  float accT[4] = {0.f,0.f,0.f,0.f};
  gemm_t_n<128, 0>(accT, Wsv0, A_T, t);
  float accU[3][4] = {};
  gemm_u_n<128>(accU, Wvv0, V_T, t);
  __syncthreads();
  {
    const int og = t & 15, e = t >> 4;
    const float as = a_s_sh[e];
    const float a0 = av_sh[e][0], a1 = av_sh[e][1], a2 = av_sh[e][2];
    #pragma unroll
    for (int j = 0; j < 4; j++){
      const int o = og*4 + j;
      const float s1v = s_buf[e][o];
      const float hs = s1v * fast_sigmoid(s1v);
      const float g  = fast_sigmoid(s_buf[e][64+o]);
      const float tt = accT[j];
      const float hv0 = (tt*a0 + as*accU[0][j]) * INV_U0 * g;
      const float hv1 = (tt*a1 + as*accU[1][j]) * INV_U0 * g;
      const float hv2 = (tt*a2 + as*accU[2][j]) * INV_U0 * g;
      A_T[o][e] = hs;
      V_T[o][e] = hv0; V_T[o][16+e] = hv1; V_T[o][32+e] = hv2;
      A_T[64+o][e] = (hv0*a0 + hv1*a1 + hv2*a2) * RSQRT3;
    }
  }
  __syncthreads();

  float sa[4] = {0.f,0.f,0.f,0.f};
  float sb[4] = {0.f,0.f,0.f,0.f};
  gemm_t_n<64, 0>(sa, Wss1, A_T, t);
  gemm_t_n<64, 64>(sb, Wvs1, A_T, t);
  float accT2[4] = {0.f,0.f,0.f,0.f};
  gemm_t_n<64, 0>(accT2, Wsv1, A_T, t);
  float accU2[3][4] = {};
  gemm_u_n<64>(accU2, Wvv1, V_T, t);
  {
    const int og = t & 15, e = t >> 4;
    const int n = n0 + e;
    const float as = a_s_sh[e];
    const float a0 = av_sh[e][0], a1 = av_sh[e][1], a2 = av_sh[e][2];
    #pragma unroll
    for (int j = 0; j < 4; j++){
      const int o = og*4 + j;
      const float us = (as*sa[j] + sb[j]) * INV_U1 + b1u[o];
      out[(size_t)n*256 + o] = node_s[(size_t)n*64 + o] + us;
      const float tt = accT2[j];
      out[(size_t)n*256 + 64 + o*3 + 0] = node_v[(size_t)n*192 + o*3 + 0] + (tt*a0 + as*accU2[0][j]) * INV_U1;
      out[(size_t)n*256 + 64 + o*3 + 1] = node_v[(size_t)n*192 + o*3 + 1] + (tt*a1 + as*accU2[1][j]) * INV_U1;
      out[(size_t)n*256 + 64 + o*3 + 2] = node_v[(size_t)n*192 + o*3 + 2] + (tt*a2 + as*accU2[2][j]) * INV_U1;
    }
  }
}

extern "C" void kernel_launch(void* const* d_in, const int* in_sizes, int n_in,
                              void* d_out, int out_size, void* d_ws, size_t ws_size,
                              hipStream_t stream) {
  const float* node_s      = (const float*)d_in[0];
  const float* node_v      = (const float*)d_in[1];
  const float* node_attr_s = (const float*)d_in[2];
  const float* node_attr_v = (const float*)d_in[3];
  const float* edge_attr_s = (const float*)d_in[4];
  const float* edge_attr_v = (const float*)d_in[5];
  const float* add_feat    = (const float*)d_in[6];
  const float* m1_Wss = (const float*)d_in[7];
  const float* m1_Wvs = (const float*)d_in[8];
  const float* m1_Wsv = (const float*)d_in[9];
  const float* m1_Wvv = (const float*)d_in[10];
  const float* m1_b   = (const float*)d_in[11];
  const float* m2_Wss = (const float*)d_in[12];
  const float* m2_Wvs = (const float*)d_in[13];
  const float* m2_Wsv = (const float*)d_in[14];
  const float* m2_Wvv = (const float*)d_in[15];
  const float* m2_b   = (const float*)d_in[16];
  const float* u0_Wss = (const float*)d_in[17];
  const float* u0_Wvs = (const float*)d_in[18];
  const float* u0_Wsv = (const float*)d_in[19];
  const float* u0_Wvv = (const float*)d_in[20];
  const float* u0_b   = (const float*)d_in[21];
  const float* u1_Wss = (const float*)d_in[22];
  const float* u1_Wvs = (const float*)d_in[23];
  const float* u1_Wsv = (const float*)d_in[24];
  const float* u1_Wvv = (const float*)d_in[25];
  const float* u1_b   = (const float*)d_in[26];
  const int* senders   = (const int*)d_in[27];
  const int* receivers = (const int*)d_in[28];
  float* out = (float*)d_out;

  // small workspace: CSR only (~2 MB)
  const size_t ELIST_BYTES = (size_t)NEDGES * sizeof(int);
  const size_t OFFS_BYTES  = (size_t)(NNODES + 1) * sizeof(int);
  const size_t CUR_BYTES   = (size_t)NNODES * sizeof(int);
  const size_t NEED = ELIST_BYTES + OFFS_BYTES + CUR_BYTES;

  hipMemsetAsync(d_out, 0, (size_t)out_size * sizeof(float), stream);

  if (ws_size >= NEED){
    char* w = (char*)d_ws;
    int* elist = (int*)w;
    int* offs  = (int*)(w + ELIST_BYTES);
    int* cnt   = (int*)(w + ELIST_BYTES + OFFS_BYTES);

    hipMemsetAsync(cnt, 0, CUR_BYTES, stream);
    hist_kernel<<<(NEDGES + 255) / 256, 256, 0, stream>>>(receivers, cnt);
    scan_kernel<<<1, 1024, 0, stream>>>(cnt, offs);
    hipMemsetAsync(cnt, 0, CUR_BYTES, stream);
    place_kernel<<<(NEDGES + 255) / 256, 256, 0, stream>>>(receivers, offs, cnt, elist);

    edge_kernel<1><<<NEDGES / ET, 64, 0, stream>>>(
        node_s, node_v, edge_attr_s, edge_attr_v, add_feat, senders, receivers, elist,
        m1_Wss, m1_Wvs, m1_Wsv, m1_Wvv, m1_b,
        m2_Wss, m2_Wvs, m2_Wsv, m2_Wvv, m2_b, out);
  } else {
    edge_kernel<0><<<NEDGES / ET, 64, 0, stream>>>(
        node_s, node_v, edge_attr_s, edge_attr_v, add_feat, senders, receivers, nullptr,
        m1_Wss, m1_Wvs, m1_Wsv, m1_Wvv, m1_b,
        m2_Wss, m2_Wvs, m2_Wsv, m2_Wvv, m2_b, out);
  }

  node_kernel<<<NNODES / TE, 256, 0, stream>>>(
      node_s, node_v, node_attr_s, node_attr_v,
      u0_Wss, u0_Wvs, u0_Wsv, u0_Wvv, u0_b,
      u1_Wss, u1_Wvs, u1_Wsv, u1_Wvv, u1_b, out);
}

// Round 7
// 1886.892 us; speedup vs baseline: 1.2130x; 1.2130x over previous
//
#include <hip/hip_runtime.h>

#define NNODES 50000
#define NEDGES 400000

// ---- node-kernel tile params ----
#define TE 16
#define AP 18
#define VP 50

// ---- edge-kernel params ----
// ET=16 edges / 64 threads = ONE wave per block. og4(16) x eg4(4) lanes,
// j=8 dual-half on 128-output gemms (gates in-lane, no sbuf), m=4 edges/lane.
// One b128 a-operand read feeds 48 FMAs. ~24 KB LDS -> 6 blocks/CU.
#define ET 16
#define QW 20      // Qreg / A2 row stride (16 + 4, float4-aligned)
#define VW 52      // VC row stride (48 + 4, float4-aligned)
#define MW 260     // LDS message row stride (float4-aligned)

// shared pool layout (floats)
#define OFF_Q   0
#define OFF_VC  2560            // 128*20
#define POOLSZ  5888            // + 64*52
// msgL overlay needs 16*260 = 4160 <= POOLSZ

constexpr float RSQRT3 = 0.57735026918962576f;
constexpr float INV_M1 = 0.062257280630559f;   // 1/sqrt(130+128)
constexpr float INV_M2 = 0.088388347648318f;   // 1/sqrt(64+64)
constexpr float INV_U0 = 0.0625f;              // 1/sqrt(128+128)
constexpr float INV_U1 = 0.088388347648318f;   // 1/sqrt(64+64)

__device__ __forceinline__ float fast_sigmoid(float x){ return 1.0f / (1.0f + __expf(-x)); }

// =====================================================================
// CSR-build kernels (ws cost: ~2 MB)
// =====================================================================
__global__ __launch_bounds__(256) void hist_kernel(const int* __restrict__ recv, int* __restrict__ cnt){
  const int e = blockIdx.x * 256 + threadIdx.x;
  if (e < NEDGES) atomicAdd(&cnt[recv[e]], 1);
}

__global__ __launch_bounds__(1024) void scan_kernel(const int* __restrict__ cnt, int* __restrict__ offs){
  __shared__ int ssum[1024];
  const int t = threadIdx.x;
  const int C = (NNODES + 1023) / 1024;   // 49
  const int base = t * C;
  int s = 0;
  for (int i = 0; i < C; i++){
    const int idx = base + i;
    if (idx < NNODES) s += cnt[idx];
  }
  ssum[t] = s;
  __syncthreads();
  for (int off = 1; off < 1024; off <<= 1){
    int v = (t >= off) ? ssum[t - off] : 0;
    __syncthreads();
    ssum[t] += v;
    __syncthreads();
  }
  int run = (t == 0) ? 0 : ssum[t - 1];
  for (int i = 0; i < C; i++){
    const int idx = base + i;
    if (idx < NNODES){ offs[idx] = run; run += cnt[idx]; }
  }
  if (t == 1023) offs[NNODES] = run;
}

__global__ __launch_bounds__(256) void place_kernel(const int* __restrict__ recv,
                                                    const int* __restrict__ offs,
                                                    int* __restrict__ cur,
                                                    int* __restrict__ elist){
  const int e = blockIdx.x * 256 + threadIdx.x;
  if (e < NEDGES){
    const int r = recv[e];
    const int p = atomicAdd(&cur[r], 1);
    elist[offs[r] + p] = e;
  }
}

// =====================================================================
// EDGE KERNEL: 16 edges / 64 threads (single wave). m1 (gated) -> m2 (gated)
// MODE 1: receiver-sorted edges, LDS run-length combine, mostly plain stores
// MODE 0: direct atomic scatter fallback
// =====================================================================
template<int MODE>
__global__ __launch_bounds__(64, 2) void edge_kernel(
    const float* __restrict__ node_s, const float* __restrict__ node_v,
    const float* __restrict__ edge_attr_s, const float* __restrict__ edge_attr_v,
    const float* __restrict__ add_feat,
    const int* __restrict__ senders, const int* __restrict__ receivers,
    const int* __restrict__ elist,
    const float* __restrict__ Wss1, const float* __restrict__ Wvs1,
    const float* __restrict__ Wsv1, const float* __restrict__ Wvv1,
    const float* __restrict__ b1,
    const float* __restrict__ Wss2, const float* __restrict__ Wvs2,
    const float* __restrict__ Wsv2, const float* __restrict__ Wvv2,
    const float* __restrict__ b2,
    float* __restrict__ out)
{
  __shared__ __align__(16) float pool[POOLSZ];
  __shared__ __align__(16) float af_sh[2][QW];
  __shared__ float as_sh[ET], av0_sh[ET], av1_sh[ET], av2_sh[ET];
  __shared__ int snd_sh[ET], rcv_sh[ET], eid_sh[ET];

  float (*Qreg)[QW] = (float(*)[QW])(pool + OFF_Q);    // 128 x 20
  float (*VC)[VW]   = (float(*)[VW])(pool + OFF_VC);   // 64 x 52
  float (*A2)[QW]   = (float(*)[QW])(pool + OFF_VC);   // phase-2 view (rows 0..31)
  float* msgL = pool;                                   // epilogue overlay, stride MW

  const int t   = threadIdx.x;
  const int e0  = blockIdx.x * ET;
  const int og4 = t & 15, eg4 = t >> 4;   // 16 outputs-groups x 4 edge-groups

  if (t < ET) eid_sh[t] = MODE ? elist[e0 + t] : (e0 + t);
  __syncthreads();

  if (t < ET){
    const int eid = eid_sh[t];
    as_sh[t]  = edge_attr_s[eid];
    snd_sh[t] = senders[eid];
    rcv_sh[t] = receivers[eid];
  } else if (t < 2*ET){
    const int e = t - ET;
    const int eid = eid_sh[e];
    av0_sh[e] = edge_attr_v[(size_t)eid*3 + 0];
    av1_sh[e] = edge_attr_v[(size_t)eid*3 + 1];
    av2_sh[e] = edge_attr_v[(size_t)eid*3 + 2];
  } else {
    const int x = t - 2*ET, e = x >> 1, d = x & 1;
    af_sh[d][e] = add_feat[(size_t)eid_sh[e]*2 + d];
  }
  __syncthreads();

  // gather role: 4 threads per edge
  const int e4 = t >> 2, q4 = t & 3;
  const float pa0 = av0_sh[e4], pa1 = av1_sh[e4], pa2 = av2_sh[e4];

  // ================= phase 1: V-tiles -> gemm_u(Wvv1) + build Q =================
  float accU[3][4][4] = {};
  for (int kt = 0; kt < 4; kt++){
    {
      const int n = (kt < 2) ? snd_sh[e4] : rcv_sh[e4];
      const float4* src = (const float4*)(node_v + (size_t)n*192) + (kt & 1)*24 + q4*6;
      float4 v0 = src[0], v1 = src[1], v2 = src[2], v3 = src[3], v4 = src[4], v5 = src[5];
      const float f[24] = {v0.x,v0.y,v0.z,v0.w, v1.x,v1.y,v1.z,v1.w,
                           v2.x,v2.y,v2.z,v2.w, v3.x,v3.y,v3.z,v3.w,
                           v4.x,v4.y,v4.z,v4.w, v5.x,v5.y,v5.z,v5.w};
      #pragma unroll
      for (int i = 0; i < 8; i++){
        const int r = q4*8 + i;
        VC[r][0*ET + e4] = f[i*3+0];
        VC[r][1*ET + e4] = f[i*3+1];
        VC[r][2*ET + e4] = f[i*3+2];
        Qreg[kt*32 + r][e4] = (f[i*3]*pa0 + f[i*3+1]*pa1 + f[i*3+2]*pa2) * RSQRT3;
      }
    }
    __syncthreads();
    const float4* W4 = (const float4*)Wvv1 + (size_t)(kt*32)*16 + og4;
    #pragma unroll 4
    for (int r = 0; r < 32; r++){
      const float4 wv = W4[(size_t)r*16];
      const float w[4] = {wv.x, wv.y, wv.z, wv.w};
      const float4 a0 = *(const float4*)&VC[r][0*ET + eg4*4];
      const float4 a1 = *(const float4*)&VC[r][1*ET + eg4*4];
      const float4 a2 = *(const float4*)&VC[r][2*ET + eg4*4];
      const float a0a[4] = {a0.x,a0.y,a0.z,a0.w};
      const float a1a[4] = {a1.x,a1.y,a1.z,a1.w};
      const float a2a[4] = {a2.x,a2.y,a2.z,a2.w};
      #pragma unroll
      for (int j = 0; j < 4; j++)
        #pragma unroll
        for (int m = 0; m < 4; m++){
          accU[0][j][m] = fmaf(w[j], a0a[m], accU[0][j][m]);
          accU[1][j][m] = fmaf(w[j], a1a[m], accU[1][j][m]);
          accU[2][j][m] = fmaf(w[j], a2a[m], accU[2][j][m]);
        }
    }
    __syncthreads();
  }

  // ====== phase 2: xs-tiles -> gemm_s(Wss1 dual-half) + gemm_t(Wsv1), shared a ======
  float accS[2][4][4] = {};   // [half][j][m]: o = half*64 + og4*4 + j, e = eg4*4 + m
  float accT[4][4] = {};
  for (int kt = 0; kt < 4; kt++){
    {
      const int n = (kt < 2) ? snd_sh[e4] : rcv_sh[e4];
      const float4* ss = (const float4*)(node_s + (size_t)n*64) + (kt & 1)*8 + q4*2;
      const float4 g0 = ss[0], g1 = ss[1];
      const float g[8] = {g0.x,g0.y,g0.z,g0.w, g1.x,g1.y,g1.z,g1.w};
      #pragma unroll
      for (int d = 0; d < 8; d++) A2[q4*8 + d][e4] = g[d];
    }
    __syncthreads();
    const float4* Wa = (const float4*)Wss1 + (size_t)(kt*32)*32 + og4;
    const float4* Wb = (const float4*)Wsv1 + (size_t)(kt*32)*16 + og4;
    #pragma unroll 4
    for (int k = 0; k < 32; k++){
      const float4 wa0 = Wa[(size_t)k*32];
      const float4 wa1 = Wa[(size_t)k*32 + 16];
      const float4 wbv = Wb[(size_t)k*16];
      const float4 a4 = *(const float4*)&A2[k][eg4*4];
      const float aa[4] = {a4.x, a4.y, a4.z, a4.w};
      const float w0[4] = {wa0.x, wa0.y, wa0.z, wa0.w};
      const float w1[4] = {wa1.x, wa1.y, wa1.z, wa1.w};
      const float wb[4] = {wbv.x, wbv.y, wbv.z, wbv.w};
      #pragma unroll
      for (int j = 0; j < 4; j++)
        #pragma unroll
        for (int m = 0; m < 4; m++){
          accS[0][j][m] = fmaf(w0[j], aa[m], accS[0][j][m]);
          accS[1][j][m] = fmaf(w1[j], aa[m], accS[1][j][m]);
          accT[j][m]    = fmaf(wb[j], aa[m], accT[j][m]);
        }
    }
    __syncthreads();
  }
  // tail rows 128..129 (add_feat)
  #pragma unroll
  for (int d = 0; d < 2; d++){
    const float4 wa0 = ((const float4*)Wss1)[(size_t)(128+d)*32 + og4];
    const float4 wa1 = ((const float4*)Wss1)[(size_t)(128+d)*32 + og4 + 16];
    const float4 wbv = ((const float4*)Wsv1)[(size_t)(128+d)*16 + og4];
    const float4 a4 = *(const float4*)&af_sh[d][eg4*4];
    const float aa[4] = {a4.x, a4.y, a4.z, a4.w};
    const float w0[4] = {wa0.x, wa0.y, wa0.z, wa0.w};
    const float w1[4] = {wa1.x, wa1.y, wa1.z, wa1.w};
    const float wb[4] = {wbv.x, wbv.y, wbv.z, wbv.w};
    #pragma unroll
    for (int j = 0; j < 4; j++)
      #pragma unroll
      for (int m = 0; m < 4; m++){
        accS[0][j][m] = fmaf(w0[j], aa[m], accS[0][j][m]);
        accS[1][j][m] = fmaf(w1[j], aa[m], accS[1][j][m]);
        accT[j][m]    = fmaf(wb[j], aa[m], accT[j][m]);
      }
  }

  // ============ phase 3: gemm_s(Wvs1, dual-half) over resident Q ============
  float accV[2][4][4] = {};
  {
    const float4* Wc = (const float4*)Wvs1 + og4;
    #pragma unroll 4
    for (int k = 0; k < 128; k++){
      const float4 wv0 = Wc[(size_t)k*32];
      const float4 wv1 = Wc[(size_t)k*32 + 16];
      const float4 a4 = *(const float4*)&Qreg[k][eg4*4];
      const float aa[4] = {a4.x, a4.y, a4.z, a4.w};
      const float w0[4] = {wv0.x, wv0.y, wv0.z, wv0.w};
      const float w1[4] = {wv1.x, wv1.y, wv1.z, wv1.w};
      #pragma unroll
      for (int j = 0; j < 4; j++)
        #pragma unroll
        for (int m = 0; m < 4; m++){
          accV[0][j][m] = fmaf(w0[j], aa[m], accV[0][j][m]);
          accV[1][j][m] = fmaf(w1[j], aa[m], accV[1][j][m]);
        }
    }
  }
  __syncthreads();   // all Qreg/VC reads done before epilogue overwrites

  // ================= m1 epilogue (all in-lane, no sbuf) =================
  {
    const float4 b1v0 = ((const float4*)b1)[og4];
    const float4 b1v1 = ((const float4*)b1)[og4 + 16];
    const float bb0[4] = {b1v0.x, b1v0.y, b1v0.z, b1v0.w};
    const float bb1[4] = {b1v1.x, b1v1.y, b1v1.z, b1v1.w};
    #pragma unroll
    for (int m = 0; m < 4; m++){
      const int e = eg4*4 + m;
      const float as = as_sh[e];
      const float a0 = av0_sh[e], a1 = av1_sh[e], a2 = av2_sh[e];
      #pragma unroll
      for (int j = 0; j < 4; j++){
        const int o = og4*4 + j;
        const float s1a = (as*accS[0][j][m] + accV[0][j][m]) * INV_M1 + bb0[j];
        const float s1b = (as*accS[1][j][m] + accV[1][j][m]) * INV_M1 + bb1[j];
        const float ms = s1a * fast_sigmoid(s1a);
        const float g  = fast_sigmoid(s1b);
        const float tt = accT[j][m];
        const float mv0 = (tt*a0 + as*accU[0][j][m]) * INV_M1 * g;
        const float mv1 = (tt*a1 + as*accU[1][j][m]) * INV_M1 * g;
        const float mv2 = (tt*a2 + as*accU[2][j][m]) * INV_M1 * g;
        Qreg[o][e]      = ms;
        Qreg[64 + o][e] = (mv0*a0 + mv1*a1 + mv2*a2) * RSQRT3;
        VC[o][0*ET + e] = mv0; VC[o][1*ET + e] = mv1; VC[o][2*ET + e] = mv2;
      }
    }
  }
  __syncthreads();

  // ================= m2 =================
  float acc2S[2][4][4] = {};
  float acc2V[2][4][4] = {};
  float acc2T[4][4] = {};
  {
    const float4* Wd = (const float4*)Wss2 + og4;
    const float4* We = (const float4*)Wvs2 + og4;
    const float4* Wf = (const float4*)Wsv2 + og4;
    #pragma unroll 4
    for (int k = 0; k < 64; k++){
      const float4 wd0 = Wd[(size_t)k*32];
      const float4 wd1 = Wd[(size_t)k*32 + 16];
      const float4 we0 = We[(size_t)k*32];
      const float4 we1 = We[(size_t)k*32 + 16];
      const float4 wfv = Wf[(size_t)k*16];
      const float4 aS4 = *(const float4*)&Qreg[k][eg4*4];
      const float4 aV4 = *(const float4*)&Qreg[64 + k][eg4*4];
      const float aS[4] = {aS4.x, aS4.y, aS4.z, aS4.w};
      const float aV[4] = {aV4.x, aV4.y, aV4.z, aV4.w};
      const float d0[4] = {wd0.x, wd0.y, wd0.z, wd0.w};
      const float d1[4] = {wd1.x, wd1.y, wd1.z, wd1.w};
      const float e0v[4] = {we0.x, we0.y, we0.z, we0.w};
      const float e1v[4] = {we1.x, we1.y, we1.z, we1.w};
      const float wf[4] = {wfv.x, wfv.y, wfv.z, wfv.w};
      #pragma unroll
      for (int j = 0; j < 4; j++)
        #pragma unroll
        for (int m = 0; m < 4; m++){
          acc2S[0][j][m] = fmaf(d0[j], aS[m], acc2S[0][j][m]);
          acc2S[1][j][m] = fmaf(d1[j], aS[m], acc2S[1][j][m]);
          acc2V[0][j][m] = fmaf(e0v[j], aV[m], acc2V[0][j][m]);
          acc2V[1][j][m] = fmaf(e1v[j], aV[m], acc2V[1][j][m]);
          acc2T[j][m]    = fmaf(wf[j], aS[m], acc2T[j][m]);
        }
    }
  }
  float acc2U[3][4][4] = {};
  {
    const float4* Wg = (const float4*)Wvv2 + og4;
    #pragma unroll 4
    for (int k = 0; k < 64; k++){
      const float4 wv = Wg[(size_t)k*16];
      const float w[4] = {wv.x, wv.y, wv.z, wv.w};
      const float4 a0 = *(const float4*)&VC[k][0*ET + eg4*4];
      const float4 a1 = *(const float4*)&VC[k][1*ET + eg4*4];
      const float4 a2 = *(const float4*)&VC[k][2*ET + eg4*4];
      const float a0a[4] = {a0.x,a0.y,a0.z,a0.w};
      const float a1a[4] = {a1.x,a1.y,a1.z,a1.w};
      const float a2a[4] = {a2.x,a2.y,a2.z,a2.w};
      #pragma unroll
      for (int j = 0; j < 4; j++)
        #pragma unroll
        for (int m = 0; m < 4; m++){
          acc2U[0][j][m] = fmaf(w[j], a0a[m], acc2U[0][j][m]);
          acc2U[1][j][m] = fmaf(w[j], a1a[m], acc2U[1][j][m]);
          acc2U[2][j][m] = fmaf(w[j], a2a[m], acc2U[2][j][m]);
        }
    }
  }
  __syncthreads();   // Qreg/VC now dead -> msgL overlay is safe

  // bias for s2, in-lane
  const float4 b2v0 = ((const float4*)b2)[og4];
  const float4 b2v1 = ((const float4*)b2)[og4 + 16];
  const float cb0[4] = {b2v0.x, b2v0.y, b2v0.z, b2v0.w};
  const float cb1[4] = {b2v1.x, b2v1.y, b2v1.z, b2v1.w};

  // ================= final epilogue =================
  if (MODE == 1){
    #pragma unroll
    for (int m = 0; m < 4; m++){
      const int e = eg4*4 + m;
      const float as = as_sh[e];
      const float a0 = av0_sh[e], a1 = av1_sh[e], a2 = av2_sh[e];
      float* base = msgL + e*MW;
      float4 sv;
      float vv[12];
      #pragma unroll
      for (int j = 0; j < 4; j++){
        const float s2a = (as*acc2S[0][j][m] + acc2V[0][j][m]) * INV_M2 + cb0[j];
        const float s2b = (as*acc2S[1][j][m] + acc2V[1][j][m]) * INV_M2 + cb1[j];
        ((float*)&sv)[j] = s2a * fast_sigmoid(s2a);
        const float g  = fast_sigmoid(s2b);
        const float tt = acc2T[j][m];
        vv[j*3 + 0] = (tt*a0 + as*acc2U[0][j][m]) * INV_M2 * g;
        vv[j*3 + 1] = (tt*a1 + as*acc2U[1][j][m]) * INV_M2 * g;
        vv[j*3 + 2] = (tt*a2 + as*acc2U[2][j][m]) * INV_M2 * g;
      }
      *(float4*)(base + og4*4) = sv;
      float4* vp = (float4*)(base + 64 + og4*12);
      vp[0] = make_float4(vv[0], vv[1], vv[2], vv[3]);
      vp[1] = make_float4(vv[4], vv[5], vv[6], vv[7]);
      vp[2] = make_float4(vv[8], vv[9], vv[10], vv[11]);
    }
    __syncthreads();
    // run-length combine over sorted receivers; each thread owns 4 features
    {
      const int f0 = t;
      float acc0 = 0.f, acc1 = 0.f, acc2 = 0.f, acc3 = 0.f;
      int seg_start = 0;
      for (int ee = 0; ee < ET; ee++){
        acc0 += msgL[ee*MW + f0];
        acc1 += msgL[ee*MW + f0 + 64];
        acc2 += msgL[ee*MW + f0 + 128];
        acc3 += msgL[ee*MW + f0 + 192];
        const int r = rcv_sh[ee];
        const bool last = (ee == ET-1);
        if (last || rcv_sh[ee+1] != r){
          float* dst = out + (size_t)r * 256;
          if (seg_start == 0 || last){       // run touches block boundary
            atomicAdd(dst + f0,       acc0);
            atomicAdd(dst + f0 + 64,  acc1);
            atomicAdd(dst + f0 + 128, acc2);
            atomicAdd(dst + f0 + 192, acc3);
          } else {                           // receiver fully owned by block
            dst[f0]       = acc0;
            dst[f0 + 64]  = acc1;
            dst[f0 + 128] = acc2;
            dst[f0 + 192] = acc3;
          }
          acc0 = 0.f; acc1 = 0.f; acc2 = 0.f; acc3 = 0.f;
          seg_start = ee + 1;
        }
      }
    }
  } else {
    #pragma unroll
    for (int m = 0; m < 4; m++){
      const int e = eg4*4 + m;
      const float as = as_sh[e];
      const float a0 = av0_sh[e], a1 = av1_sh[e], a2 = av2_sh[e];
      float* base = out + (size_t)rcv_sh[e] * 256;
      #pragma unroll
      for (int j = 0; j < 4; j++){
        const int o = og4*4 + j;
        const float s2a = (as*acc2S[0][j][m] + acc2V[0][j][m]) * INV_M2 + cb0[j];
        const float s2b = (as*acc2S[1][j][m] + acc2V[1][j][m]) * INV_M2 + cb1[j];
        atomicAdd(base + o, s2a * fast_sigmoid(s2a));
        const float g  = fast_sigmoid(s2b);
        const float tt = acc2T[j][m];
        atomicAdd(base + 64 + o*3 + 0, (tt*a0 + as*acc2U[0][j][m]) * INV_M2 * g);
        atomicAdd(base + 64 + o*3 + 1, (tt*a1 + as*acc2U[1][j][m]) * INV_M2 * g);
        atomicAdd(base + 64 + o*3 + 2, (tt*a2 + as*acc2U[2][j][m]) * INV_M2 * g);
      }
    }
  }
}

// =====================================================================
// NODE KERNEL: u0 (gated) -> u1 -> residual
// =====================================================================
template<int K, int ROWBASE>
__device__ __forceinline__ void gemm_s_n(float acc[4][2], const float* __restrict__ W,
                                         float (*A_T)[AP], int t){
  const int og = t & 31;
  const int eg = t >> 5;
  const float4* __restrict__ W4 = (const float4*)W;
  #pragma unroll 8
  for (int k = 0; k < K; k++){
    const float4 w = W4[k*32 + og];
    const float2 a = *(const float2*)(&A_T[ROWBASE + k][eg*2]);
    acc[0][0] = fmaf(w.x, a.x, acc[0][0]); acc[0][1] = fmaf(w.x, a.y, acc[0][1]);
    acc[1][0] = fmaf(w.y, a.x, acc[1][0]); acc[1][1] = fmaf(w.y, a.y, acc[1][1]);
    acc[2][0] = fmaf(w.z, a.x, acc[2][0]); acc[2][1] = fmaf(w.z, a.y, acc[2][1]);
    acc[3][0] = fmaf(w.w, a.x, acc[3][0]); acc[3][1] = fmaf(w.w, a.y, acc[3][1]);
  }
}

template<int K, int ROWBASE>
__device__ __forceinline__ void gemm_t_n(float acc[4], const float* __restrict__ W,
                                         float (*A_T)[AP], int t){
  const int og = t & 15;
  const int eg = t >> 4;
  const float4* __restrict__ W4 = (const float4*)W;
  #pragma unroll 8
  for (int k = 0; k < K; k++){
    const float4 w = W4[k*16 + og];
    const float a = A_T[ROWBASE + k][eg];
    acc[0] = fmaf(w.x, a, acc[0]); acc[1] = fmaf(w.y, a, acc[1]);
    acc[2] = fmaf(w.z, a, acc[2]); acc[3] = fmaf(w.w, a, acc[3]);
  }
}

template<int K>
__device__ __forceinline__ void gemm_u_n(float acc[3][4], const float* __restrict__ W,
                                         float (*V_T)[VP], int t){
  const int og = t & 15;
  const int eg = t >> 4;
  const float4* __restrict__ W4 = (const float4*)W;
  #pragma unroll 4
  for (int k = 0; k < K; k++){
    const float4 w = W4[k*16 + og];
    const float a0 = V_T[k][eg], a1 = V_T[k][16+eg], a2 = V_T[k][32+eg];
    acc[0][0] = fmaf(w.x,a0,acc[0][0]); acc[0][1] = fmaf(w.y,a0,acc[0][1]);
    acc[0][2] = fmaf(w.z,a0,acc[0][2]); acc[0][3] = fmaf(w.w,a0,acc[0][3]);
    acc[1][0] = fmaf(w.x,a1,acc[1][0]); acc[1][1] = fmaf(w.y,a1,acc[1][1]);
    acc[1][2] = fmaf(w.z,a1,acc[1][2]); acc[1][3] = fmaf(w.w,a1,acc[1][3]);
    acc[2][0] = fmaf(w.x,a2,acc[2][0]); acc[2][1] = fmaf(w.y,a2,acc[2][1]);
    acc[2][2] = fmaf(w.z,a2,acc[2][2]); acc[2][3] = fmaf(w.w,a2,acc[2][3]);
  }
}

__global__ __launch_bounds__(256, 3) void node_kernel(
    const float* __restrict__ node_s, const float* __restrict__ node_v,
    const float* __restrict__ node_attr_s, const float* __restrict__ node_attr_v,
    const float* __restrict__ Wss0, const float* __restrict__ Wvs0,
    const float* __restrict__ Wsv0, const float* __restrict__ Wvv0,
    const float* __restrict__ b0,
    const float* __restrict__ Wss1, const float* __restrict__ Wvs1,
    const float* __restrict__ Wsv1, const float* __restrict__ Wvv1,
    const float* __restrict__ b1u,
    float* __restrict__ out)
{
  __shared__ float A_T[256][AP];
  __shared__ float V_T[128][VP];
  __shared__ float s_buf[TE][129];
  __shared__ float a_s_sh[TE];
  __shared__ float av_sh[TE][3];

  const int t = threadIdx.x;
  const int n0 = blockIdx.x * TE;

  if (t < TE) a_s_sh[t] = node_attr_s[n0 + t];
  if (t < TE*3) av_sh[t/3][t%3] = node_attr_v[n0*3 + t];
  {
    const int e = t >> 4, l = t & 15;
    const int n = n0 + e;
    float4 v4 = ((const float4*)(node_s + (size_t)n*64))[l];
    A_T[l*4+0][e] = v4.x; A_T[l*4+1][e] = v4.y;
    A_T[l*4+2][e] = v4.z; A_T[l*4+3][e] = v4.w;
    v4 = ((const float4*)(out + (size_t)n*256))[l];
    A_T[64+l*4+0][e] = v4.x; A_T[64+l*4+1][e] = v4.y;
    A_T[64+l*4+2][e] = v4.z; A_T[64+l*4+3][e] = v4.w;
    const float4* pvn = (const float4*)(node_v + (size_t)n*192);
    const float4* pva = (const float4*)(out + (size_t)n*256 + 64);
    #pragma unroll
    for (int q = 0; q < 3; q++){
      float4 w4 = pvn[l*3+q];
      int f = (l*3+q)*4;
      float vals[4] = {w4.x, w4.y, w4.z, w4.w};
      #pragma unroll
      for (int j = 0; j < 4; j++){
        int ff = f + j, vv = ff/3, ii = ff - vv*3;
        V_T[vv][ii*16 + e] = vals[j];
      }
      w4 = pva[l*3+q];
      float vals2[4] = {w4.x, w4.y, w4.z, w4.w};
      #pragma unroll
      for (int j = 0; j < 4; j++){
        int ff = f + j, vv = ff/3, ii = ff - vv*3;
        V_T[64 + vv][ii*16 + e] = vals2[j];
      }
    }
  }
  __syncthreads();
  {
    const int e = t >> 4, l = t & 15;
    const float a0 = av_sh[e][0], a1 = av_sh[e][1], a2 = av_sh[e][2];
    #pragma unroll
    for (int r = 0; r < 8; r++){
      int v = l*8 + r;
      float q = V_T[v][e]*a0 + V_T[v][16+e]*a1 + V_T[v][32+e]*a2;
      A_T[128 + v][e] = q * RSQRT3;
    }
  }
  __syncthreads();

  float acc_a[4][2] = {{0.f,0.f},{0.f,0.f},{0.f,0.f},{0.f,0.f}};
  float acc_b[4][2] = {{0.f,0.f},{0.f,0.f},{0.f,0.f},{0.f,0.f}};
  gemm_s_n<128, 0>(acc_a, Wss0, A_T, t);
  gemm_s_n<128, 128>(acc_b, Wvs0, A_T, t);
  {
    const int og = t & 31, eg = t >> 5;
    #pragma unroll
    for (int m = 0; m < 2; m++){
      const int e = eg*2 + m;
      const float as = a_s_sh[e];
      #pragma unroll
      for (int j = 0; j < 4; j++){
        const int o = og*4 + j;
        s_buf[e][o] = (as*acc_a[j][m] + acc_b[j][m]) * INV_U0 + b0[o];
      }
    }
  }
  float accT[4] = {0.f,0.f,0.f,0.f};
  gemm_t_n<128, 0>(accT, Wsv0, A_T, t);
  float accU[3][4] = {};
  gemm_u_n<128>(accU, Wvv0, V_T, t);
  __syncthreads();
  {
    const int og = t & 15, e = t >> 4;
    const float as = a_s_sh[e];
    const float a0 = av_sh[e][0], a1 = av_sh[e][1], a2 = av_sh[e][2];
    #pragma unroll
    for (int j = 0; j < 4; j++){
      const int o = og*4 + j;
      const float s1v = s_buf[e][o];
      const float hs = s1v * fast_sigmoid(s1v);
      const float g  = fast_sigmoid(s_buf[e][64+o]);
      const float tt = accT[j];
      const float hv0 = (tt*a0 + as*accU[0][j]) * INV_U0 * g;
      const float hv1 = (tt*a1 + as*accU[1][j]) * INV_U0 * g;
      const float hv2 = (tt*a2 + as*accU[2][j]) * INV_U0 * g;
      A_T[o][e] = hs;
      V_T[o][e] = hv0; V_T[o][16+e] = hv1; V_T[o][32+e] = hv2;
      A_T[64+o][e] = (hv0*a0 + hv1*a1 + hv2*a2) * RSQRT3;
    }
  }
  __syncthreads();

  float sa[4] = {0.f,0.f,0.f,0.f};
  float sb[4] = {0.f,0.f,0.f,0.f};
  gemm_t_n<64, 0>(sa, Wss1, A_T, t);
  gemm_t_n<64, 64>(sb, Wvs1, A_T, t);
  float accT2[4] = {0.f,0.f,0.f,0.f};
  gemm_t_n<64, 0>(accT2, Wsv1, A_T, t);
  float accU2[3][4] = {};
  gemm_u_n<64>(accU2, Wvv1, V_T, t);
  {
    const int og = t & 15, e = t >> 4;
    const int n = n0 + e;
    const float as = a_s_sh[e];
    const float a0 = av_sh[e][0], a1 = av_sh[e][1], a2 = av_sh[e][2];
    #pragma unroll
    for (int j = 0; j < 4; j++){
      const int o = og*4 + j;
      const float us = (as*sa[j] + sb[j]) * INV_U1 + b1u[o];
      out[(size_t)n*256 + o] = node_s[(size_t)n*64 + o] + us;
      const float tt = accT2[j];
      out[(size_t)n*256 + 64 + o*3 + 0] = node_v[(size_t)n*192 + o*3 + 0] + (tt*a0 + as*accU2[0][j]) * INV_U1;
      out[(size_t)n*256 + 64 + o*3 + 1] = node_v[(size_t)n*192 + o*3 + 1] + (tt*a1 + as*accU2[1][j]) * INV_U1;
      out[(size_t)n*256 + 64 + o*3 + 2] = node_v[(size_t)n*192 + o*3 + 2] + (tt*a2 + as*accU2[2][j]) * INV_U1;
    }
  }
}

extern "C" void kernel_launch(void* const* d_in, const int* in_sizes, int n_in,
                              void* d_out, int out_size, void* d_ws, size_t ws_size,
                              hipStream_t stream) {
  const float* node_s      = (const float*)d_in[0];
  const float* node_v      = (const float*)d_in[1];
  const float* node_attr_s = (const float*)d_in[2];
  const float* node_attr_v = (const float*)d_in[3];
  const float* edge_attr_s = (const float*)d_in[4];
  const float* edge_attr_v = (const float*)d_in[5];
  const float* add_feat    = (const float*)d_in[6];
  const float* m1_Wss = (const float*)d_in[7];
  const float* m1_Wvs = (const float*)d_in[8];
  const float* m1_Wsv = (const float*)d_in[9];
  const float* m1_Wvv = (const float*)d_in[10];
  const float* m1_b   = (const float*)d_in[11];
  const float* m2_Wss = (const float*)d_in[12];
  const float* m2_Wvs = (const float*)d_in[13];
  const float* m2_Wsv = (const float*)d_in[14];
  const float* m2_Wvv = (const float*)d_in[15];
  const float* m2_b   = (const float*)d_in[16];
  const float* u0_Wss = (const float*)d_in[17];
  const float* u0_Wvs = (const float*)d_in[18];
  const float* u0_Wsv = (const float*)d_in[19];
  const float* u0_Wvv = (const float*)d_in[20];
  const float* u0_b   = (const float*)d_in[21];
  const float* u1_Wss = (const float*)d_in[22];
  const float* u1_Wvs = (const float*)d_in[23];
  const float* u1_Wsv = (const float*)d_in[24];
  const float* u1_Wvv = (const float*)d_in[25];
  const float* u1_b   = (const float*)d_in[26];
  const int* senders   = (const int*)d_in[27];
  const int* receivers = (const int*)d_in[28];
  float* out = (float*)d_out;

  // small workspace: CSR only (~2 MB)
  const size_t ELIST_BYTES = (size_t)NEDGES * sizeof(int);
  const size_t OFFS_BYTES  = (size_t)(NNODES + 1) * sizeof(int);
  const size_t CUR_BYTES   = (size_t)NNODES * sizeof(int);
  const size_t NEED = ELIST_BYTES + OFFS_BYTES + CUR_BYTES;

  hipMemsetAsync(d_out, 0, (size_t)out_size * sizeof(float), stream);

  if (ws_size >= NEED){
    char* w = (char*)d_ws;
    int* elist = (int*)w;
    int* offs  = (int*)(w + ELIST_BYTES);
    int* cnt   = (int*)(w + ELIST_BYTES + OFFS_BYTES);

    hipMemsetAsync(cnt, 0, CUR_BYTES, stream);
    hist_kernel<<<(NEDGES + 255) / 256, 256, 0, stream>>>(receivers, cnt);
    scan_kernel<<<1, 1024, 0, stream>>>(cnt, offs);
    hipMemsetAsync(cnt, 0, CUR_BYTES, stream);
    place_kernel<<<(NEDGES + 255) / 256, 256, 0, stream>>>(receivers, offs, cnt, elist);

    edge_kernel<1><<<NEDGES / ET, 64, 0, stream>>>(
        node_s, node_v, edge_attr_s, edge_attr_v, add_feat, senders, receivers, elist,
        m1_Wss, m1_Wvs, m1_Wsv, m1_Wvv, m1_b,
        m2_Wss, m2_Wvs, m2_Wsv, m2_Wvv, m2_b, out);
  } else {
    edge_kernel<0><<<NEDGES / ET, 64, 0, stream>>>(
        node_s, node_v, edge_attr_s, edge_attr_v, add_feat, senders, receivers, nullptr,
        m1_Wss, m1_Wvs, m1_Wsv, m1_Wvv, m1_b,
        m2_Wss, m2_Wvs, m2_Wsv, m2_Wvv, m2_b, out);
  }

  node_kernel<<<NNODES / TE, 256, 0, stream>>>(
      node_s, node_v, node_attr_s, node_attr_v,
      u0_Wss, u0_Wvs, u0_Wsv, u0_Wvv, u0_b,
      u1_Wss, u1_Wvs, u1_Wsv, u1_Wvv, u1_b, out);
}

// Round 8
// 1755.849 us; speedup vs baseline: 1.3035x; 1.0746x over previous
//
#include <hip/hip_runtime.h>

#define NNODES 50000
#define NEDGES 400000

// ---- node-kernel tile params ----
#define TE 16
#define AP 18
#define VP 50

// ---- edge-kernel params ----
// ET=16 edges / 64 threads = ONE wave per block (R7 structure, 1478us) with
// m2 split into two stages so ms/q2 and mv LDS buffers never co-reside.
// Peak pool = phase1 (Q[128][20] + VCs[32][52]) = 4224 floats -> ~17.5 KB
// total LDS -> 9 blocks/CU (2.25 waves/SIMD) vs R7's 6.
#define ET 16
#define QW 20      // Q / A2s / MSQ row stride (16 + 4, float4-aligned)
#define VW 52      // VCs / MV row stride (48 + 4, float4-aligned)
#define MW 260     // LDS message row stride (float4-aligned)

// shared pool layout (floats)
#define OFF_ST  2560            // staging (VCs / A2s) after Q[128][20]
#define POOLSZ  4224            // 2560 + 32*52
// overlays @0: MV[64][52]=3328, MSQ[128][20]=2560, msgL 16*260=4160 (all <= 4224)

constexpr float RSQRT3 = 0.57735026918962576f;
constexpr float INV_M1 = 0.062257280630559f;   // 1/sqrt(130+128)
constexpr float INV_M2 = 0.088388347648318f;   // 1/sqrt(64+64)
constexpr float INV_U0 = 0.0625f;              // 1/sqrt(128+128)
constexpr float INV_U1 = 0.088388347648318f;   // 1/sqrt(64+64)

__device__ __forceinline__ float fast_sigmoid(float x){ return 1.0f / (1.0f + __expf(-x)); }

// =====================================================================
// CSR-build kernels (ws cost: ~2 MB)
// =====================================================================
__global__ __launch_bounds__(256) void hist_kernel(const int* __restrict__ recv, int* __restrict__ cnt){
  const int e = blockIdx.x * 256 + threadIdx.x;
  if (e < NEDGES) atomicAdd(&cnt[recv[e]], 1);
}

__global__ __launch_bounds__(1024) void scan_kernel(const int* __restrict__ cnt, int* __restrict__ offs){
  __shared__ int ssum[1024];
  const int t = threadIdx.x;
  const int C = (NNODES + 1023) / 1024;   // 49
  const int base = t * C;
  int s = 0;
  for (int i = 0; i < C; i++){
    const int idx = base + i;
    if (idx < NNODES) s += cnt[idx];
  }
  ssum[t] = s;
  __syncthreads();
  for (int off = 1; off < 1024; off <<= 1){
    int v = (t >= off) ? ssum[t - off] : 0;
    __syncthreads();
    ssum[t] += v;
    __syncthreads();
  }
  int run = (t == 0) ? 0 : ssum[t - 1];
  for (int i = 0; i < C; i++){
    const int idx = base + i;
    if (idx < NNODES){ offs[idx] = run; run += cnt[idx]; }
  }
  if (t == 1023) offs[NNODES] = run;
}

__global__ __launch_bounds__(256) void place_kernel(const int* __restrict__ recv,
                                                    const int* __restrict__ offs,
                                                    int* __restrict__ cur,
                                                    int* __restrict__ elist){
  const int e = blockIdx.x * 256 + threadIdx.x;
  if (e < NEDGES){
    const int r = recv[e];
    const int p = atomicAdd(&cur[r], 1);
    elist[offs[r] + p] = e;
  }
}

// =====================================================================
// EDGE KERNEL: 16 edges / 64 threads (single wave). m1 (gated) -> m2 (gated)
// MODE 1: receiver-sorted edges, LDS run-length combine, mostly plain stores
// MODE 0: direct atomic scatter fallback
// =====================================================================
template<int MODE>
__global__ __launch_bounds__(64, 2) void edge_kernel(
    const float* __restrict__ node_s, const float* __restrict__ node_v,
    const float* __restrict__ edge_attr_s, const float* __restrict__ edge_attr_v,
    const float* __restrict__ add_feat,
    const int* __restrict__ senders, const int* __restrict__ receivers,
    const int* __restrict__ elist,
    const float* __restrict__ Wss1, const float* __restrict__ Wvs1,
    const float* __restrict__ Wsv1, const float* __restrict__ Wvv1,
    const float* __restrict__ b1,
    const float* __restrict__ Wss2, const float* __restrict__ Wvs2,
    const float* __restrict__ Wsv2, const float* __restrict__ Wvv2,
    const float* __restrict__ b2,
    float* __restrict__ out)
{
  __shared__ __align__(16) float pool[POOLSZ];
  __shared__ __align__(16) float af_sh[2][QW];
  __shared__ float as_sh[ET], av0_sh[ET], av1_sh[ET], av2_sh[ET];
  __shared__ int snd_sh[ET], rcv_sh[ET], eid_sh[ET];

  float (*Qb)[QW]   = (float(*)[QW])(pool);            // 128 x 20 (phases 1-3)
  float (*VCs)[VW]  = (float(*)[VW])(pool + OFF_ST);   // 32 x 52 (phase-1 staging)
  float (*A2s)[QW]  = (float(*)[QW])(pool + OFF_ST);   // 32 x 20 (phase-2 staging)
  float (*MV)[VW]   = (float(*)[VW])(pool);            // 64 x 52 (m2 stage A: mv)
  float (*MSQ)[QW]  = (float(*)[QW])(pool);            // 128 x 20 (m2 stage B: ms/q2)
  float* msgL = pool;                                   // epilogue overlay, stride MW

  const int t   = threadIdx.x;
  const int e0  = blockIdx.x * ET;
  const int og4 = t & 15, eg4 = t >> 4;   // 16 output-groups x 4 edge-groups

  if (t < ET) eid_sh[t] = MODE ? elist[e0 + t] : (e0 + t);
  __syncthreads();

  if (t < ET){
    const int eid = eid_sh[t];
    as_sh[t]  = edge_attr_s[eid];
    snd_sh[t] = senders[eid];
    rcv_sh[t] = receivers[eid];
  } else if (t < 2*ET){
    const int e = t - ET;
    const int eid = eid_sh[e];
    av0_sh[e] = edge_attr_v[(size_t)eid*3 + 0];
    av1_sh[e] = edge_attr_v[(size_t)eid*3 + 1];
    av2_sh[e] = edge_attr_v[(size_t)eid*3 + 2];
  } else {
    const int x = t - 2*ET, e = x >> 1, d = x & 1;
    af_sh[d][e] = add_feat[(size_t)eid_sh[e]*2 + d];
  }
  __syncthreads();

  // gather role: 4 threads per edge
  const int e4 = t >> 2, q4 = t & 3;
  const float pa0 = av0_sh[e4], pa1 = av1_sh[e4], pa2 = av2_sh[e4];

  // ================= phase 1: V-tiles -> gemm_u(Wvv1) + build Q =================
  float accU[3][4][4] = {};
  for (int kt = 0; kt < 4; kt++){
    {
      const int n = (kt < 2) ? snd_sh[e4] : rcv_sh[e4];
      const float4* src = (const float4*)(node_v + (size_t)n*192) + (kt & 1)*24 + q4*6;
      float4 v0 = src[0], v1 = src[1], v2 = src[2], v3 = src[3], v4 = src[4], v5 = src[5];
      const float f[24] = {v0.x,v0.y,v0.z,v0.w, v1.x,v1.y,v1.z,v1.w,
                           v2.x,v2.y,v2.z,v2.w, v3.x,v3.y,v3.z,v3.w,
                           v4.x,v4.y,v4.z,v4.w, v5.x,v5.y,v5.z,v5.w};
      #pragma unroll
      for (int i = 0; i < 8; i++){
        const int r = q4*8 + i;
        VCs[r][0*ET + e4] = f[i*3+0];
        VCs[r][1*ET + e4] = f[i*3+1];
        VCs[r][2*ET + e4] = f[i*3+2];
        Qb[kt*32 + r][e4] = (f[i*3]*pa0 + f[i*3+1]*pa1 + f[i*3+2]*pa2) * RSQRT3;
      }
    }
    __syncthreads();
    const float4* W4 = (const float4*)Wvv1 + (size_t)(kt*32)*16 + og4;
    #pragma unroll 4
    for (int r = 0; r < 32; r++){
      const float4 wv = W4[(size_t)r*16];
      const float w[4] = {wv.x, wv.y, wv.z, wv.w};
      const float4 a0 = *(const float4*)&VCs[r][0*ET + eg4*4];
      const float4 a1 = *(const float4*)&VCs[r][1*ET + eg4*4];
      const float4 a2 = *(const float4*)&VCs[r][2*ET + eg4*4];
      const float a0a[4] = {a0.x,a0.y,a0.z,a0.w};
      const float a1a[4] = {a1.x,a1.y,a1.z,a1.w};
      const float a2a[4] = {a2.x,a2.y,a2.z,a2.w};
      #pragma unroll
      for (int j = 0; j < 4; j++)
        #pragma unroll
        for (int m = 0; m < 4; m++){
          accU[0][j][m] = fmaf(w[j], a0a[m], accU[0][j][m]);
          accU[1][j][m] = fmaf(w[j], a1a[m], accU[1][j][m]);
          accU[2][j][m] = fmaf(w[j], a2a[m], accU[2][j][m]);
        }
    }
    __syncthreads();
  }

  // ====== phase 2: xs-tiles -> gemm_s(Wss1 dual-half) + gemm_t(Wsv1), shared a ======
  float accS[2][4][4] = {};   // [half][j][m]: o = half*64 + og4*4 + j, e = eg4*4 + m
  float accT[4][4] = {};
  for (int kt = 0; kt < 4; kt++){
    {
      const int n = (kt < 2) ? snd_sh[e4] : rcv_sh[e4];
      const float4* ss = (const float4*)(node_s + (size_t)n*64) + (kt & 1)*8 + q4*2;
      const float4 g0 = ss[0], g1 = ss[1];
      const float g[8] = {g0.x,g0.y,g0.z,g0.w, g1.x,g1.y,g1.z,g1.w};
      #pragma unroll
      for (int d = 0; d < 8; d++) A2s[q4*8 + d][e4] = g[d];
    }
    __syncthreads();
    const float4* Wa = (const float4*)Wss1 + (size_t)(kt*32)*32 + og4;
    const float4* Wb = (const float4*)Wsv1 + (size_t)(kt*32)*16 + og4;
    #pragma unroll 4
    for (int k = 0; k < 32; k++){
      const float4 wa0 = Wa[(size_t)k*32];
      const float4 wa1 = Wa[(size_t)k*32 + 16];
      const float4 wbv = Wb[(size_t)k*16];
      const float4 a4 = *(const float4*)&A2s[k][eg4*4];
      const float aa[4] = {a4.x, a4.y, a4.z, a4.w};
      const float w0[4] = {wa0.x, wa0.y, wa0.z, wa0.w};
      const float w1[4] = {wa1.x, wa1.y, wa1.z, wa1.w};
      const float wb[4] = {wbv.x, wbv.y, wbv.z, wbv.w};
      #pragma unroll
      for (int j = 0; j < 4; j++)
        #pragma unroll
        for (int m = 0; m < 4; m++){
          accS[0][j][m] = fmaf(w0[j], aa[m], accS[0][j][m]);
          accS[1][j][m] = fmaf(w1[j], aa[m], accS[1][j][m]);
          accT[j][m]    = fmaf(wb[j], aa[m], accT[j][m]);
        }
    }
    __syncthreads();
  }
  // tail rows 128..129 (add_feat)
  #pragma unroll
  for (int d = 0; d < 2; d++){
    const float4 wa0 = ((const float4*)Wss1)[(size_t)(128+d)*32 + og4];
    const float4 wa1 = ((const float4*)Wss1)[(size_t)(128+d)*32 + og4 + 16];
    const float4 wbv = ((const float4*)Wsv1)[(size_t)(128+d)*16 + og4];
    const float4 a4 = *(const float4*)&af_sh[d][eg4*4];
    const float aa[4] = {a4.x, a4.y, a4.z, a4.w};
    const float w0[4] = {wa0.x, wa0.y, wa0.z, wa0.w};
    const float w1[4] = {wa1.x, wa1.y, wa1.z, wa1.w};
    const float wb[4] = {wbv.x, wbv.y, wbv.z, wbv.w};
    #pragma unroll
    for (int j = 0; j < 4; j++)
      #pragma unroll
      for (int m = 0; m < 4; m++){
        accS[0][j][m] = fmaf(w0[j], aa[m], accS[0][j][m]);
        accS[1][j][m] = fmaf(w1[j], aa[m], accS[1][j][m]);
        accT[j][m]    = fmaf(wb[j], aa[m], accT[j][m]);
      }
  }

  // ============ phase 3: gemm_s(Wvs1, dual-half) over resident Q ============
  float accV[2][4][4] = {};
  {
    const float4* Wc = (const float4*)Wvs1 + og4;
    #pragma unroll 4
    for (int k = 0; k < 128; k++){
      const float4 wv0 = Wc[(size_t)k*32];
      const float4 wv1 = Wc[(size_t)k*32 + 16];
      const float4 a4 = *(const float4*)&Qb[k][eg4*4];
      const float aa[4] = {a4.x, a4.y, a4.z, a4.w};
      const float w0[4] = {wv0.x, wv0.y, wv0.z, wv0.w};
      const float w1[4] = {wv1.x, wv1.y, wv1.z, wv1.w};
      #pragma unroll
      for (int j = 0; j < 4; j++)
        #pragma unroll
        for (int m = 0; m < 4; m++){
          accV[0][j][m] = fmaf(w0[j], aa[m], accV[0][j][m]);
          accV[1][j][m] = fmaf(w1[j], aa[m], accV[1][j][m]);
        }
    }
  }
  __syncthreads();   // Q dead; MV overlay may now overwrite pool[0..)

  // ===== m1 epilogue: ms/q2 -> registers, mv -> MV LDS =====
  float msr[4][4], q2r[4][4];
  {
    const float4 b1v0 = ((const float4*)b1)[og4];
    const float4 b1v1 = ((const float4*)b1)[og4 + 16];
    const float bb0[4] = {b1v0.x, b1v0.y, b1v0.z, b1v0.w};
    const float bb1[4] = {b1v1.x, b1v1.y, b1v1.z, b1v1.w};
    #pragma unroll
    for (int m = 0; m < 4; m++){
      const int e = eg4*4 + m;
      const float as = as_sh[e];
      const float a0 = av0_sh[e], a1 = av1_sh[e], a2 = av2_sh[e];
      #pragma unroll
      for (int j = 0; j < 4; j++){
        const int o = og4*4 + j;
        const float s1a = (as*accS[0][j][m] + accV[0][j][m]) * INV_M1 + bb0[j];
        const float s1b = (as*accS[1][j][m] + accV[1][j][m]) * INV_M1 + bb1[j];
        const float ms = s1a * fast_sigmoid(s1a);
        const float g  = fast_sigmoid(s1b);
        const float tt = accT[j][m];
        const float mv0 = (tt*a0 + as*accU[0][j][m]) * INV_M1 * g;
        const float mv1 = (tt*a1 + as*accU[1][j][m]) * INV_M1 * g;
        const float mv2 = (tt*a2 + as*accU[2][j][m]) * INV_M1 * g;
        msr[j][m] = ms;
        q2r[j][m] = (mv0*a0 + mv1*a1 + mv2*a2) * RSQRT3;
        MV[o][0*ET + e] = mv0; MV[o][1*ET + e] = mv1; MV[o][2*ET + e] = mv2;
      }
    }
  }
  __syncthreads();

  // ===== m2 stage A: gemm_u(Wvv2) over MV =====
  float acc2U[3][4][4] = {};
  {
    const float4* Wg = (const float4*)Wvv2 + og4;
    #pragma unroll 4
    for (int k = 0; k < 64; k++){
      const float4 wv = Wg[(size_t)k*16];
      const float w[4] = {wv.x, wv.y, wv.z, wv.w};
      const float4 a0 = *(const float4*)&MV[k][0*ET + eg4*4];
      const float4 a1 = *(const float4*)&MV[k][1*ET + eg4*4];
      const float4 a2 = *(const float4*)&MV[k][2*ET + eg4*4];
      const float a0a[4] = {a0.x,a0.y,a0.z,a0.w};
      const float a1a[4] = {a1.x,a1.y,a1.z,a1.w};
      const float a2a[4] = {a2.x,a2.y,a2.z,a2.w};
      #pragma unroll
      for (int j = 0; j < 4; j++)
        #pragma unroll
        for (int m = 0; m < 4; m++){
          acc2U[0][j][m] = fmaf(w[j], a0a[m], acc2U[0][j][m]);
          acc2U[1][j][m] = fmaf(w[j], a1a[m], acc2U[1][j][m]);
          acc2U[2][j][m] = fmaf(w[j], a2a[m], acc2U[2][j][m]);
        }
    }
  }
  __syncthreads();   // MV reads done; MSQ overlay may overwrite

  // ===== m2 stage B: write ms/q2 from regs, then Wss2/Wvs2/Wsv2 =====
  {
    #pragma unroll
    for (int m = 0; m < 4; m++){
      const int e = eg4*4 + m;
      #pragma unroll
      for (int j = 0; j < 4; j++){
        const int o = og4*4 + j;
        MSQ[o][e]      = msr[j][m];
        MSQ[64 + o][e] = q2r[j][m];
      }
    }
  }
  __syncthreads();

  float acc2S[2][4][4] = {};
  float acc2V[2][4][4] = {};
  float acc2T[4][4] = {};
  {
    const float4* Wd = (const float4*)Wss2 + og4;
    const float4* We = (const float4*)Wvs2 + og4;
    const float4* Wf = (const float4*)Wsv2 + og4;
    #pragma unroll 4
    for (int k = 0; k < 64; k++){
      const float4 wd0 = Wd[(size_t)k*32];
      const float4 wd1 = Wd[(size_t)k*32 + 16];
      const float4 we0 = We[(size_t)k*32];
      const float4 we1 = We[(size_t)k*32 + 16];
      const float4 wfv = Wf[(size_t)k*16];
      const float4 aS4 = *(const float4*)&MSQ[k][eg4*4];
      const float4 aV4 = *(const float4*)&MSQ[64 + k][eg4*4];
      const float aS[4] = {aS4.x, aS4.y, aS4.z, aS4.w};
      const float aV[4] = {aV4.x, aV4.y, aV4.z, aV4.w};
      const float d0[4] = {wd0.x, wd0.y, wd0.z, wd0.w};
      const float d1[4] = {wd1.x, wd1.y, wd1.z, wd1.w};
      const float e0v[4] = {we0.x, we0.y, we0.z, we0.w};
      const float e1v[4] = {we1.x, we1.y, we1.z, we1.w};
      const float wf[4] = {wfv.x, wfv.y, wfv.z, wfv.w};
      #pragma unroll
      for (int j = 0; j < 4; j++)
        #pragma unroll
        for (int m = 0; m < 4; m++){
          acc2S[0][j][m] = fmaf(d0[j], aS[m], acc2S[0][j][m]);
          acc2S[1][j][m] = fmaf(d1[j], aS[m], acc2S[1][j][m]);
          acc2V[0][j][m] = fmaf(e0v[j], aV[m], acc2V[0][j][m]);
          acc2V[1][j][m] = fmaf(e1v[j], aV[m], acc2V[1][j][m]);
          acc2T[j][m]    = fmaf(wf[j], aS[m], acc2T[j][m]);
        }
    }
  }
  __syncthreads();   // MSQ dead -> msgL overlay is safe

  // bias for s2, in-lane
  const float4 b2v0 = ((const float4*)b2)[og4];
  const float4 b2v1 = ((const float4*)b2)[og4 + 16];
  const float cb0[4] = {b2v0.x, b2v0.y, b2v0.z, b2v0.w};
  const float cb1[4] = {b2v1.x, b2v1.y, b2v1.z, b2v1.w};

  // ================= final epilogue =================
  if (MODE == 1){
    #pragma unroll
    for (int m = 0; m < 4; m++){
      const int e = eg4*4 + m;
      const float as = as_sh[e];
      const float a0 = av0_sh[e], a1 = av1_sh[e], a2 = av2_sh[e];
      float* base = msgL + e*MW;
      float4 sv;
      float vv[12];
      #pragma unroll
      for (int j = 0; j < 4; j++){
        const float s2a = (as*acc2S[0][j][m] + acc2V[0][j][m]) * INV_M2 + cb0[j];
        const float s2b = (as*acc2S[1][j][m] + acc2V[1][j][m]) * INV_M2 + cb1[j];
        ((float*)&sv)[j] = s2a * fast_sigmoid(s2a);
        const float g  = fast_sigmoid(s2b);
        const float tt = acc2T[j][m];
        vv[j*3 + 0] = (tt*a0 + as*acc2U[0][j][m]) * INV_M2 * g;
        vv[j*3 + 1] = (tt*a1 + as*acc2U[1][j][m]) * INV_M2 * g;
        vv[j*3 + 2] = (tt*a2 + as*acc2U[2][j][m]) * INV_M2 * g;
      }
      *(float4*)(base + og4*4) = sv;
      float4* vp = (float4*)(base + 64 + og4*12);
      vp[0] = make_float4(vv[0], vv[1], vv[2], vv[3]);
      vp[1] = make_float4(vv[4], vv[5], vv[6], vv[7]);
      vp[2] = make_float4(vv[8], vv[9], vv[10], vv[11]);
    }
    __syncthreads();
    // run-length combine over sorted receivers; each thread owns 4 features
    {
      const int f0 = t;
      float acc0 = 0.f, acc1 = 0.f, acc2 = 0.f, acc3 = 0.f;
      int seg_start = 0;
      for (int ee = 0; ee < ET; ee++){
        acc0 += msgL[ee*MW + f0];
        acc1 += msgL[ee*MW + f0 + 64];
        acc2 += msgL[ee*MW + f0 + 128];
        acc3 += msgL[ee*MW + f0 + 192];
        const int r = rcv_sh[ee];
        const bool last = (ee == ET-1);
        if (last || rcv_sh[ee+1] != r){
          float* dst = out + (size_t)r * 256;
          if (seg_start == 0 || last){       // run touches block boundary
            atomicAdd(dst + f0,       acc0);
            atomicAdd(dst + f0 + 64,  acc1);
            atomicAdd(dst + f0 + 128, acc2);
            atomicAdd(dst + f0 + 192, acc3);
          } else {                           // receiver fully owned by block
            dst[f0]       = acc0;
            dst[f0 + 64]  = acc1;
            dst[f0 + 128] = acc2;
            dst[f0 + 192] = acc3;
          }
          acc0 = 0.f; acc1 = 0.f; acc2 = 0.f; acc3 = 0.f;
          seg_start = ee + 1;
        }
      }
    }
  } else {
    #pragma unroll
    for (int m = 0; m < 4; m++){
      const int e = eg4*4 + m;
      const float as = as_sh[e];
      const float a0 = av0_sh[e], a1 = av1_sh[e], a2 = av2_sh[e];
      float* base = out + (size_t)rcv_sh[e] * 256;
      #pragma unroll
      for (int j = 0; j < 4; j++){
        const int o = og4*4 + j;
        const float s2a = (as*acc2S[0][j][m] + acc2V[0][j][m]) * INV_M2 + cb0[j];
        const float s2b = (as*acc2S[1][j][m] + acc2V[1][j][m]) * INV_M2 + cb1[j];
        atomicAdd(base + o, s2a * fast_sigmoid(s2a));
        const float g  = fast_sigmoid(s2b);
        const float tt = acc2T[j][m];
        atomicAdd(base + 64 + o*3 + 0, (tt*a0 + as*acc2U[0][j][m]) * INV_M2 * g);
        atomicAdd(base + 64 + o*3 + 1, (tt*a1 + as*acc2U[1][j][m]) * INV_M2 * g);
        atomicAdd(base + 64 + o*3 + 2, (tt*a2 + as*acc2U[2][j][m]) * INV_M2 * g);
      }
    }
  }
}

// =====================================================================
// NODE KERNEL: u0 (gated) -> u1 -> residual
// =====================================================================
template<int K, int ROWBASE>
__device__ __forceinline__ void gemm_s_n(float acc[4][2], const float* __restrict__ W,
                                         float (*A_T)[AP], int t){
  const int og = t & 31;
  const int eg = t >> 5;
  const float4* __restrict__ W4 = (const float4*)W;
  #pragma unroll 8
  for (int k = 0; k < K; k++){
    const float4 w = W4[k*32 + og];
    const float2 a = *(const float2*)(&A_T[ROWBASE + k][eg*2]);
    acc[0][0] = fmaf(w.x, a.x, acc[0][0]); acc[0][1] = fmaf(w.x, a.y, acc[0][1]);
    acc[1][0] = fmaf(w.y, a.x, acc[1][0]); acc[1][1] = fmaf(w.y, a.y, acc[1][1]);
    acc[2][0] = fmaf(w.z, a.x, acc[2][0]); acc[2][1] = fmaf(w.z, a.y, acc[2][1]);
    acc[3][0] = fmaf(w.w, a.x, acc[3][0]); acc[3][1] = fmaf(w.w, a.y, acc[3][1]);
  }
}

template<int K, int ROWBASE>
__device__ __forceinline__ void gemm_t_n(float acc[4], const float* __restrict__ W,
                                         float (*A_T)[AP], int t){
  const int og = t & 15;
  const int eg = t >> 4;
  const float4* __restrict__ W4 = (const float4*)W;
  #pragma unroll 8
  for (int k = 0; k < K; k++){
    const float4 w = W4[k*16 + og];
    const float a = A_T[ROWBASE + k][eg];
    acc[0] = fmaf(w.x, a, acc[0]); acc[1] = fmaf(w.y, a, acc[1]);
    acc[2] = fmaf(w.z, a, acc[2]); acc[3] = fmaf(w.w, a, acc[3]);
  }
}

template<int K>
__device__ __forceinline__ void gemm_u_n(float acc[3][4], const float* __restrict__ W,
                                         float (*V_T)[VP], int t){
  const int og = t & 15;
  const int eg = t >> 4;
  const float4* __restrict__ W4 = (const float4*)W;
  #pragma unroll 4
  for (int k = 0; k < K; k++){
    const float4 w = W4[k*16 + og];
    const float a0 = V_T[k][eg], a1 = V_T[k][16+eg], a2 = V_T[k][32+eg];
    acc[0][0] = fmaf(w.x,a0,acc[0][0]); acc[0][1] = fmaf(w.y,a0,acc[0][1]);
    acc[0][2] = fmaf(w.z,a0,acc[0][2]); acc[0][3] = fmaf(w.w,a0,acc[0][3]);
    acc[1][0] = fmaf(w.x,a1,acc[1][0]); acc[1][1] = fmaf(w.y,a1,acc[1][1]);
    acc[1][2] = fmaf(w.z,a1,acc[1][2]); acc[1][3] = fmaf(w.w,a1,acc[1][3]);
    acc[2][0] = fmaf(w.x,a2,acc[2][0]); acc[2][1] = fmaf(w.y,a2,acc[2][1]);
    acc[2][2] = fmaf(w.z,a2,acc[2][2]); acc[2][3] = fmaf(w.w,a2,acc[2][3]);
  }
}

__global__ __launch_bounds__(256, 3) void node_kernel(
    const float* __restrict__ node_s, const float* __restrict__ node_v,
    const float* __restrict__ node_attr_s, const float* __restrict__ node_attr_v,
    const float* __restrict__ Wss0, const float* __restrict__ Wvs0,
    const float* __restrict__ Wsv0, const float* __restrict__ Wvv0,
    const float* __restrict__ b0,
    const float* __restrict__ Wss1, const float* __restrict__ Wvs1,
    const float* __restrict__ Wsv1, const float* __restrict__ Wvv1,
    const float* __restrict__ b1u,
    float* __restrict__ out)
{
  __shared__ float A_T[256][AP];
  __shared__ float V_T[128][VP];
  __shared__ float s_buf[TE][129];
  __shared__ float a_s_sh[TE];
  __shared__ float av_sh[TE][3];

  const int t = threadIdx.x;
  const int n0 = blockIdx.x * TE;

  if (t < TE) a_s_sh[t] = node_attr_s[n0 + t];
  if (t < TE*3) av_sh[t/3][t%3] = node_attr_v[n0*3 + t];
  {
    const int e = t >> 4, l = t & 15;
    const int n = n0 + e;
    float4 v4 = ((const float4*)(node_s + (size_t)n*64))[l];
    A_T[l*4+0][e] = v4.x; A_T[l*4+1][e] = v4.y;
    A_T[l*4+2][e] = v4.z; A_T[l*4+3][e] = v4.w;
    v4 = ((const float4*)(out + (size_t)n*256))[l];
    A_T[64+l*4+0][e] = v4.x; A_T[64+l*4+1][e] = v4.y;
    A_T[64+l*4+2][e] = v4.z; A_T[64+l*4+3][e] = v4.w;
    const float4* pvn = (const float4*)(node_v + (size_t)n*192);
    const float4* pva = (const float4*)(out + (size_t)n*256 + 64);
    #pragma unroll
    for (int q = 0; q < 3; q++){
      float4 w4 = pvn[l*3+q];
      int f = (l*3+q)*4;
      float vals[4] = {w4.x, w4.y, w4.z, w4.w};
      #pragma unroll
      for (int j = 0; j < 4; j++){
        int ff = f + j, vv = ff/3, ii = ff - vv*3;
        V_T[vv][ii*16 + e] = vals[j];
      }
      w4 = pva[l*3+q];
      float vals2[4] = {w4.x, w4.y, w4.z, w4.w};
      #pragma unroll
      for (int j = 0; j < 4; j++){
        int ff = f + j, vv = ff/3, ii = ff - vv*3;
        V_T[64 + vv][ii*16 + e] = vals2[j];
      }
    }
  }
  __syncthreads();
  {
    const int e = t >> 4, l = t & 15;
    const float a0 = av_sh[e][0], a1 = av_sh[e][1], a2 = av_sh[e][2];
    #pragma unroll
    for (int r = 0; r < 8; r++){
      int v = l*8 + r;
      float q = V_T[v][e]*a0 + V_T[v][16+e]*a1 + V_T[v][32+e]*a2;
      A_T[128 + v][e] = q * RSQRT3;
    }
  }
  __syncthreads();

  float acc_a[4][2] = {{0.f,0.f},{0.f,0.f},{0.f,0.f},{0.f,0.f}};
  float acc_b[4][2] = {{0.f,0.f},{0.f,0.f},{0.f,0.f},{0.f,0.f}};
  gemm_s_n<128, 0>(acc_a, Wss0, A_T, t);
  gemm_s_n<128, 128>(acc_b, Wvs0, A_T, t);
  {
    const int og = t & 31, eg = t >> 5;
    #pragma unroll
    for (int m = 0; m < 2; m++){
      const int e = eg*2 + m;
      const float as = a_s_sh[e];
      #pragma unroll
      for (int j = 0; j < 4; j++){
        const int o = og*4 + j;
        s_buf[e][o] = (as*acc_a[j][m] + acc_b[j][m]) * INV_U0 + b0[o];
      }
    }
  }
  float accT[4] = {0.f,0.f,0.f,0.f};
  gemm_t_n<128, 0>(accT, Wsv0, A_T, t);
  float accU[3][4] = {};
  gemm_u_n<128>(accU, Wvv0, V_T, t);
  __syncthreads();
  {
    const int og = t & 15, e = t >> 4;
    const float as = a_s_sh[e];
    const float a0 = av_sh[e][0], a1 = av_sh[e][1], a2 = av_sh[e][2];
    #pragma unroll
    for (int j = 0; j < 4; j++){
      const int o = og*4 + j;
      const float s1v = s_buf[e][o];
      const float hs = s1v * fast_sigmoid(s1v);
      const float g  = fast_sigmoid(s_buf[e][64+o]);
      const float tt = accT[j];
      const float hv0 = (tt*a0 + as*accU[0][j]) * INV_U0 * g;
      const float hv1 = (tt*a1 + as*accU[1][j]) * INV_U0 * g;
      const float hv2 = (tt*a2 + as*accU[2][j]) * INV_U0 * g;
      A_T[o][e] = hs;
      V_T[o][e] = hv0; V_T[o][16+e] = hv1; V_T[o][32+e] = hv2;
      A_T[64+o][e] = (hv0*a0 + hv1*a1 + hv2*a2) * RSQRT3;
    }
  }
  __syncthreads();

  float sa[4] = {0.f,0.f,0.f,0.f};
  float sb[4] = {0.f,0.f,0.f,0.f};
  gemm_t_n<64, 0>(sa, Wss1, A_T, t);
  gemm_t_n<64, 64>(sb, Wvs1, A_T, t);
  float accT2[4] = {0.f,0.f,0.f,0.f};
  gemm_t_n<64, 0>(accT2, Wsv1, A_T, t);
  float accU2[3][4] = {};
  gemm_u_n<64>(accU2, Wvv1, V_T, t);
  {
    const int og = t & 15, e = t >> 4;
    const int n = n0 + e;
    const float as = a_s_sh[e];
    const float a0 = av_sh[e][0], a1 = av_sh[e][1], a2 = av_sh[e][2];
    #pragma unroll
    for (int j = 0; j < 4; j++){
      const int o = og*4 + j;
      const float us = (as*sa[j] + sb[j]) * INV_U1 + b1u[o];
      out[(size_t)n*256 + o] = node_s[(size_t)n*64 + o] + us;
      const float tt = accT2[j];
      out[(size_t)n*256 + 64 + o*3 + 0] = node_v[(size_t)n*192 + o*3 + 0] + (tt*a0 + as*accU2[0][j]) * INV_U1;
      out[(size_t)n*256 + 64 + o*3 + 1] = node_v[(size_t)n*192 + o*3 + 1] + (tt*a1 + as*accU2[1][j]) * INV_U1;
      out[(size_t)n*256 + 64 + o*3 + 2] = node_v[(size_t)n*192 + o*3 + 2] + (tt*a2 + as*accU2[2][j]) * INV_U1;
    }
  }
}

extern "C" void kernel_launch(void* const* d_in, const int* in_sizes, int n_in,
                              void* d_out, int out_size, void* d_ws, size_t ws_size,
                              hipStream_t stream) {
  const float* node_s      = (const float*)d_in[0];
  const float* node_v      = (const float*)d_in[1];
  const float* node_attr_s = (const float*)d_in[2];
  const float* node_attr_v = (const float*)d_in[3];
  const float* edge_attr_s = (const float*)d_in[4];
  const float* edge_attr_v = (const float*)d_in[5];
  const float* add_feat    = (const float*)d_in[6];
  const float* m1_Wss = (const float*)d_in[7];
  const float* m1_Wvs = (const float*)d_in[8];
  const float* m1_Wsv = (const float*)d_in[9];
  const float* m1_Wvv = (const float*)d_in[10];
  const float* m1_b   = (const float*)d_in[11];
  const float* m2_Wss = (const float*)d_in[12];
  const float* m2_Wvs = (const float*)d_in[13];
  const float* m2_Wsv = (const float*)d_in[14];
  const float* m2_Wvv = (const float*)d_in[15];
  const float* m2_b   = (const float*)d_in[16];
  const float* u0_Wss = (const float*)d_in[17];
  const float* u0_Wvs = (const float*)d_in[18];
  const float* u0_Wsv = (const float*)d_in[19];
  const float* u0_Wvv = (const float*)d_in[20];
  const float* u0_b   = (const float*)d_in[21];
  const float* u1_Wss = (const float*)d_in[22];
  const float* u1_Wvs = (const float*)d_in[23];
  const float* u1_Wsv = (const float*)d_in[24];
  const float* u1_Wvv = (const float*)d_in[25];
  const float* u1_b   = (const float*)d_in[26];
  const int* senders   = (const int*)d_in[27];
  const int* receivers = (const int*)d_in[28];
  float* out = (float*)d_out;

  // small workspace: CSR only (~2 MB)
  const size_t ELIST_BYTES = (size_t)NEDGES * sizeof(int);
  const size_t OFFS_BYTES  = (size_t)(NNODES + 1) * sizeof(int);
  const size_t CUR_BYTES   = (size_t)NNODES * sizeof(int);
  const size_t NEED = ELIST_BYTES + OFFS_BYTES + CUR_BYTES;

  hipMemsetAsync(d_out, 0, (size_t)out_size * sizeof(float), stream);

  if (ws_size >= NEED){
    char* w = (char*)d_ws;
    int* elist = (int*)w;
    int* offs  = (int*)(w + ELIST_BYTES);
    int* cnt   = (int*)(w + ELIST_BYTES + OFFS_BYTES);

    hipMemsetAsync(cnt, 0, CUR_BYTES, stream);
    hist_kernel<<<(NEDGES + 255) / 256, 256, 0, stream>>>(receivers, cnt);
    scan_kernel<<<1, 1024, 0, stream>>>(cnt, offs);
    hipMemsetAsync(cnt, 0, CUR_BYTES, stream);
    place_kernel<<<(NEDGES + 255) / 256, 256, 0, stream>>>(receivers, offs, cnt, elist);

    edge_kernel<1><<<NEDGES / ET, 64, 0, stream>>>(
        node_s, node_v, edge_attr_s, edge_attr_v, add_feat, senders, receivers, elist,
        m1_Wss, m1_Wvs, m1_Wsv, m1_Wvv, m1_b,
        m2_Wss, m2_Wvs, m2_Wsv, m2_Wvv, m2_b, out);
  } else {
    edge_kernel<0><<<NEDGES / ET, 64, 0, stream>>>(
        node_s, node_v, edge_attr_s, edge_attr_v, add_feat, senders, receivers, nullptr,
        m1_Wss, m1_Wvs, m1_Wsv, m1_Wvv, m1_b,
        m2_Wss, m2_Wvs, m2_Wsv, m2_Wvv, m2_b, out);
  }

  node_kernel<<<NNODES / TE, 256, 0, stream>>>(
      node_s, node_v, node_attr_s, node_attr_v,
      u0_Wss, u0_Wvs, u0_Wsv, u0_Wvv, u0_b,
      u1_Wss, u1_Wvs, u1_Wsv, u1_Wvv, u1_b, out);
}